// Round 8
// baseline (1105.754 us; speedup 1.0000x reference)
//
#include <hip/hip_runtime.h>

#define NND 100000   // nodes
#define NED 400000   // edges
#define FEAT 143
#define FEATP 160
#define EDIM 6
#define H 128
#define NG 4096      // graphs
#define NBS 391      // ceil(NND/256)

typedef __attribute__((ext_vector_type(8))) short bf8;
typedef __attribute__((ext_vector_type(4))) float f4;

__device__ __forceinline__ float b2f(unsigned short u){
  unsigned int x = ((unsigned int)u) << 16;
  return __builtin_bit_cast(float, x);
}
__device__ __forceinline__ unsigned short f2b(float f){
  unsigned int u = __builtin_bit_cast(unsigned int, f);
  u = u + 0x7fffu + ((u >> 16) & 1u);   // RNE
  return (unsigned short)(u >> 16);
}
__device__ __forceinline__ float lk(float v){ return v >= 0.f ? v : 0.01f*v; }
__device__ __forceinline__ float eluf(float v){ return v > 0.f ? v : __expf(v) - 1.f; }
__device__ __forceinline__ float sgm(float v){ return 1.f/(1.f + __expf(-v)); }
__device__ __forceinline__ float wsum(float v){
  #pragma unroll
  for(int o=32;o>0;o>>=1) v += __shfl_xor(v,o);
  return v;
}
// 16B-aligned fp32x8 -> bf16x8
__device__ __forceinline__ bf8 cvt8(const float* p){
  f4 a = *(const f4*)p;
  f4 b = *(const f4*)(p+4);
  bf8 t;
  t[0]=(short)f2b(a[0]); t[1]=(short)f2b(a[1]); t[2]=(short)f2b(a[2]); t[3]=(short)f2b(a[3]);
  t[4]=(short)f2b(b[0]); t[5]=(short)f2b(b[1]); t[6]=(short)f2b(b[2]); t[7]=(short)f2b(b[3]);
  return t;
}

// ---------------- weight fp32 -> bf16 MFMA-fragment order ----------------
__global__ __launch_bounds__(256) void k_wfrag(const float* __restrict__ src, int lds, int srcK,
                                               unsigned short* __restrict__ dst, int NT, int KB){
  int i = blockIdx.x*256 + threadIdx.x;
  int total = NT*KB*512;
  if (i >= total) return;
  int j = i & 7, lane = (i>>3) & 63, kb = (i>>9) % KB, nt = i/(KB*512);
  int n = nt*16 + (lane & 15), k = kb*32 + (lane>>4)*8 + j;
  dst[i] = (k < srcK) ? f2b(src[(size_t)n*lds + k]) : (unsigned short)0;
}

// ---------------- CSR build (counting sort of edges by dst) ----------------
__global__ __launch_bounds__(256) void k_hist(const int* __restrict__ ei, int* __restrict__ deg){
  int e = blockIdx.x*256 + threadIdx.x;
  if (e < NED) atomicAdd(&deg[ei[NED + e]], 1);
}
__global__ __launch_bounds__(256) void k_scan1(const int* __restrict__ deg, int* __restrict__ off, int* __restrict__ bsum){
  __shared__ int s[256];
  int i = blockIdx.x*256 + threadIdx.x;
  int v = (i < NND) ? deg[i] : 0;
  s[threadIdx.x] = v; __syncthreads();
  for(int o=1;o<256;o<<=1){
    int t = 0; if (threadIdx.x >= o) t = s[threadIdx.x - o];
    __syncthreads(); s[threadIdx.x] += t; __syncthreads();
  }
  if (i < NND) off[i] = s[threadIdx.x] - v;
  if (threadIdx.x == 255) bsum[blockIdx.x] = s[255];
}
__global__ __launch_bounds__(512) void k_scan2(int* __restrict__ bsum){
  __shared__ int s[512];
  int t = threadIdx.x;
  int v = (t < NBS) ? bsum[t] : 0;
  s[t] = v; __syncthreads();
  for(int o=1;o<512;o<<=1){
    int x = 0; if (t >= o) x = s[t - o];
    __syncthreads(); s[t] += x; __syncthreads();
  }
  if (t < NBS) bsum[t] = s[t] - v;
  if (t == 511) bsum[NBS] = s[511];
}
__global__ __launch_bounds__(256) void k_scan3(int* __restrict__ off, const int* __restrict__ bsum, int* __restrict__ cursor){
  int i = blockIdx.x*256 + threadIdx.x;
  if (i < NND){
    int v = off[i] + bsum[blockIdx.x];
    off[i] = v; cursor[i] = v;
  }
  if (i == 0) off[NND] = bsum[NBS];
}
__global__ __launch_bounds__(256) void k_scatter(const int* __restrict__ ei, int* __restrict__ cursor, int* __restrict__ perm){
  int e = blockIdx.x*256 + threadIdx.x;
  if (e < NED){
    int p = atomicAdd(&cursor[ei[NED + e]], 1);
    perm[p] = e;
  }
}
__global__ __launch_bounds__(256) void k_gstart(const int* __restrict__ batch, int* __restrict__ goff){
  int i = blockIdx.x*256 + threadIdx.x;
  if (i >= NND) return;
  int bi = batch[i];
  int bp = (i > 0) ? batch[i-1] : -1;
  for(int g = bp+1; g <= bi; g++) goff[g] = i;
  if (i == NND-1) for(int g = bi+1; g <= NG; g++) goff[g] = NND;
}

// ---------------- pad + fp32->bf16 for lin1 A (K=143 -> 160) ----------------
__global__ __launch_bounds__(256) void k_padx(const float* __restrict__ x, unsigned short* __restrict__ xp){
  int r = blockIdx.x*4 + (threadIdx.x >> 6);
  int lane = threadIdx.x & 63;
  if (r >= NND) return;
  for(int i = lane; i < FEATP; i += 64)
    xp[(size_t)r*FEATP + i] = (i < FEAT) ? f2b(x[(size_t)r*FEAT + i]) : (unsigned short)0;
}

// ---------------- MFMA GEMM with optional fused row-dot epilogue ----------------
// C[M,128] = act(A @ W^T + bias); DOT>=1: o1[row] += C_row . v1 (atomic); DOT==2: also v2->o2.
template<int KB, int RT, bool ABF16, bool BIAS, int ACT, bool OBF16, int DOT>
__global__ __launch_bounds__(256) void k_gemm(const void* __restrict__ Ap, int lda,
        const unsigned short* __restrict__ Wf,
        const float* __restrict__ bias, void* __restrict__ Cp, int M,
        const float* __restrict__ v1, const float* __restrict__ v2,
        float* __restrict__ o1, float* __restrict__ o2)
{
  int tid = threadIdx.x, wave = tid >> 6, lane = tid & 63;
  int m = lane & 15, quad = lane >> 4;
  int r0 = blockIdx.x * (16*RT);
  bf8 a[RT][KB];
  #pragma unroll
  for(int rt=0; rt<RT; rt++){
    int row = r0 + rt*16 + m;
    if (ABF16){
      const unsigned short* base = (const unsigned short*)Ap + (size_t)row*lda + quad*8;
      #pragma unroll
      for(int kb=0;kb<KB;kb++) a[rt][kb] = *(const bf8*)(base + kb*32);
    } else {
      const float* base = (const float*)Ap + (size_t)row*lda + quad*8;
      #pragma unroll
      for(int kb=0;kb<KB;kb++) a[rt][kb] = cvt8(base + kb*32);
    }
  }
  float d1[RT][4], d2[RT][4];
  if (DOT >= 1){
    #pragma unroll
    for(int rt=0;rt<RT;rt++)
      #pragma unroll
      for(int i=0;i<4;i++){ d1[rt][i] = 0.f; if (DOT==2) d2[rt][i] = 0.f; }
  }
  #pragma unroll
  for(int ct=0;ct<2;ct++){
    int nt = wave*2 + ct;
    int n = nt*16 + m;
    const bf8* wf = (const bf8*)Wf + (size_t)nt*KB*64;
    bf8 b[KB];
    #pragma unroll
    for(int kb=0;kb<KB;kb++) b[kb] = wf[kb*64 + lane];
    float bv = BIAS ? bias[n] : 0.f;
    float vv1 = (DOT>=1) ? v1[n] : 0.f;
    float vv2 = (DOT==2) ? v2[n] : 0.f;
    #pragma unroll
    for(int rt=0;rt<RT;rt++){
      f4 acc = {0.f,0.f,0.f,0.f};
      #pragma unroll
      for(int kb=0;kb<KB;kb++)
        acc = __builtin_amdgcn_mfma_f32_16x16x32_bf16(a[rt][kb], b[kb], acc, 0, 0, 0);
      #pragma unroll
      for(int i=0;i<4;i++){
        int row = r0 + rt*16 + quad*4 + i;
        float v = acc[i] + bv;
        if (ACT == 1) v = lk(v);
        if (DOT >= 1){ d1[rt][i] += v*vv1; if (DOT==2) d2[rt][i] += v*vv2; }
        if (row < M){
          if (OBF16) ((unsigned short*)Cp)[(size_t)row*H + n] = f2b(v);
          else       ((float*)Cp)[(size_t)row*H + n] = v;
        }
      }
    }
  }
  if (DOT >= 1){
    #pragma unroll
    for(int rt=0;rt<RT;rt++){
      #pragma unroll
      for(int i=0;i<4;i++){
        float dd = d1[rt][i];
        #pragma unroll
        for(int o=1;o<16;o<<=1) dd += __shfl_xor(dd, o);
        int row = r0 + rt*16 + quad*4 + i;
        if (m == 0 && row < M) atomicAdd(&o1[row], dd);
        if (DOT == 2){
          float ee = d2[rt][i];
          #pragma unroll
          for(int o=1;o<16;o<<=1) ee += __shfl_xor(ee, o);
          if (m == 0 && row < M) atomicAdd(&o2[row], ee);
        }
      }
    }
  }
}

// ---------------- dual GEMM for GATEConv: ux = interleave(A@W1^T, A@W2^T) bf16 ----------------
// ux[row][ (n>>3)*16 + ws*8 + (n&7) ]  (512B rows: per 16-lane sub, [u 8 | x2 8])
__global__ __launch_bounds__(256) void k_gemm2(const float* __restrict__ A,
        const unsigned short* __restrict__ Wf1, const unsigned short* __restrict__ Wf2,
        unsigned short* __restrict__ ux, int M)
{
  int tid = threadIdx.x, wave = tid >> 6, lane = tid & 63;
  int m = lane & 15, quad = lane >> 4;
  int r0 = blockIdx.x * 64;
  bf8 a[4][4];
  #pragma unroll
  for(int rt=0; rt<4; rt++){
    const float* base = A + (size_t)(r0 + rt*16 + m)*H + quad*8;
    #pragma unroll
    for(int kb=0;kb<4;kb++) a[rt][kb] = cvt8(base + kb*32);
  }
  #pragma unroll
  for(int ws=0; ws<2; ws++){
    const unsigned short* Wf = ws ? Wf2 : Wf1;
    #pragma unroll
    for(int ct=0;ct<2;ct++){
      int nt = wave*2 + ct;
      int n = nt*16 + m;
      const bf8* wf = (const bf8*)Wf + (size_t)nt*256;
      bf8 b[4];
      #pragma unroll
      for(int kb=0;kb<4;kb++) b[kb] = wf[kb*64 + lane];
      int pos = (n>>3)*16 + ws*8 + (n&7);
      #pragma unroll
      for(int rt=0;rt<4;rt++){
        f4 acc = {0.f,0.f,0.f,0.f};
        #pragma unroll
        for(int kb=0;kb<4;kb++)
          acc = __builtin_amdgcn_mfma_f32_16x16x32_bf16(a[rt][kb], b[kb], acc, 0, 0, 0);
        #pragma unroll
        for(int i=0;i<4;i++){
          int row = r0 + rt*16 + quad*4 + i;
          if (row < M) ux[(size_t)row*256 + pos] = f2b(acc[i]);
        }
      }
    }
  }
}

// ---------------- fused MFMA GRU v4 (fragment-ordered weights, 32 rows/block) ----------------
__global__ __launch_bounds__(256) void k_gru(const float* __restrict__ Xin,
      const float* __restrict__ Hid, float* __restrict__ Out,
      const unsigned short* __restrict__ Wif, const unsigned short* __restrict__ Whf,
      const float* __restrict__ bi, const float* __restrict__ bh_)
{
  int tid = threadIdx.x, wave = tid >> 6, lane = tid & 63;
  int m = lane & 15, quad = lane >> 4;
  int r0 = blockIdx.x * 32;
  bf8 ax[2][4], ah[2][4];
  #pragma unroll
  for(int rt=0;rt<2;rt++){
    const float* xb = Xin + (size_t)(r0+rt*16+m)*H + quad*8;
    const float* hb = Hid + (size_t)(r0+rt*16+m)*H + quad*8;
    #pragma unroll
    for(int kb=0;kb<4;kb++){
      ax[rt][kb] = cvt8(xb + kb*32);
      ah[rt][kb] = cvt8(hb + kb*32);
    }
  }
  __syncthreads();   // all A-frag reads of (possibly aliased) Hid done before any store
  f4 rg[2][2], ng[2][2];
  #pragma unroll
  for(int c=0;c<2;c++){
    int nt = wave*2 + c;
    const bf8* wi = (const bf8*)Wif + (size_t)nt*256;
    const bf8* wh = (const bf8*)Whf + (size_t)nt*256;
    int col = nt*16 + m;
    float bb = bi[col] + bh_[col];
    #pragma unroll
    for(int rt=0;rt<2;rt++){
      f4 acc = {0.f,0.f,0.f,0.f};
      #pragma unroll
      for(int kb=0;kb<4;kb++){
        acc = __builtin_amdgcn_mfma_f32_16x16x32_bf16(ax[rt][kb], wi[kb*64+lane], acc,0,0,0);
        acc = __builtin_amdgcn_mfma_f32_16x16x32_bf16(ah[rt][kb], wh[kb*64+lane], acc,0,0,0);
      }
      #pragma unroll
      for(int i=0;i<4;i++) rg[c][rt][i] = sgm(acc[i] + bb);
    }
  }
  #pragma unroll
  for(int c=0;c<2;c++){
    int nt = 16 + wave*2 + c;
    const bf8* wi = (const bf8*)Wif + (size_t)nt*256;
    const bf8* wh = (const bf8*)Whf + (size_t)nt*256;
    int col = (wave*2+c)*16 + m;
    float bin_ = bi[col+256], bhn_ = bh_[col+256];
    #pragma unroll
    for(int rt=0;rt<2;rt++){
      f4 a1 = {0.f,0.f,0.f,0.f}, a2 = {0.f,0.f,0.f,0.f};
      #pragma unroll
      for(int kb=0;kb<4;kb++){
        a1 = __builtin_amdgcn_mfma_f32_16x16x32_bf16(ax[rt][kb], wi[kb*64+lane], a1,0,0,0);
        a2 = __builtin_amdgcn_mfma_f32_16x16x32_bf16(ah[rt][kb], wh[kb*64+lane], a2,0,0,0);
      }
      #pragma unroll
      for(int i=0;i<4;i++)
        ng[c][rt][i] = tanhf(a1[i] + bin_ + rg[c][rt][i]*(a2[i] + bhn_));
    }
  }
  #pragma unroll
  for(int c=0;c<2;c++){
    int nt = 8 + wave*2 + c;
    const bf8* wi = (const bf8*)Wif + (size_t)nt*256;
    const bf8* wh = (const bf8*)Whf + (size_t)nt*256;
    int col = (wave*2+c)*16 + m;
    float bb = bi[col+128] + bh_[col+128];
    #pragma unroll
    for(int rt=0;rt<2;rt++){
      f4 acc = {0.f,0.f,0.f,0.f};
      #pragma unroll
      for(int kb=0;kb<4;kb++){
        acc = __builtin_amdgcn_mfma_f32_16x16x32_bf16(ax[rt][kb], wi[kb*64+lane], acc,0,0,0);
        acc = __builtin_amdgcn_mfma_f32_16x16x32_bf16(ah[rt][kb], wh[kb*64+lane], acc,0,0,0);
      }
      #pragma unroll
      for(int i=0;i<4;i++){
        float zg = sgm(acc[i] + bb);
        int row = r0 + rt*16 + quad*4 + i;
        float hv = Hid[(size_t)row*H + col];
        float o = (1.f - zg)*ng[c][rt][i] + zg*hv;
        Out[(size_t)row*H + col] = fmaxf(o, 0.f);
      }
    }
  }
}

// ---------------- GATEConv: online-softmax aggregation, reg-resident W1e, unified ux gather ----------------
__global__ __launch_bounds__(256) void k_gate_agg(
   const int* __restrict__ ei, const float* __restrict__ eattr,
   const float* __restrict__ gcW, const float* __restrict__ attl,
   const float* __restrict__ r, const unsigned short* __restrict__ ux,
   const float* __restrict__ gbias,
   const int* __restrict__ off, const int* __restrict__ perm,
   float* __restrict__ hout)
{
  int tid = threadIdx.x;
  int wave = tid >> 6, lane = tid & 63;
  int grp = lane >> 4, sub = lane & 15;
  int n = blockIdx.x*4 + wave;
  if (n >= NND) return;
  int c0 = sub*8;
  float W1e[48];        // edge-linear weights for this lane's 8 cols
  #pragma unroll
  for(int c=0;c<8;c++)
    #pragma unroll
    for(int j=0;j<EDIM;j++)
      W1e[c*EDIM+j] = gcW[(size_t)(c0+c)*(H+EDIM) + H + j];
  float attl8[8];
  #pragma unroll
  for(int c=0;c<8;c++) attl8[c] = attl[c0+c];
  int o0 = off[n], deg = off[n+1] - o0;
  float rn = r[n];
  float mx = -3.4e38f, S = 0.f;
  float acc[8] = {0,0,0,0,0,0,0,0};
  for(int base=0; base<deg; base+=64){
    int cnt = min(deg - base, 64);
    int e_l = 0, s_l = 0;
    if (lane < cnt){ e_l = perm[o0 + base + lane]; s_l = ei[e_l]; }
    #pragma unroll 1
    for(int k=0;k<16;k++){
      int l = grp + k*4;
      if (l >= cnt) break;
      int e = __shfl(e_l, l);
      int s = __shfl(s_l, l);
      const float* ep = eattr + (size_t)e*EDIM;
      const unsigned short* rowp = ux + (size_t)s*256 + sub*16;
      bf8 uv = *(const bf8*)rowp;
      bf8 xv = *(const bf8*)(rowp + 8);
      float p = 0.f;
      #pragma unroll
      for(int c=0;c<8;c++){
        float ve = 0.f;
        #pragma unroll
        for(int j=0;j<EDIM;j++) ve += ep[j] * W1e[c*EDIM + j];
        float t = lk(b2f((unsigned short)uv[c]) + ve);
        p += t * attl8[c];
      }
      #pragma unroll
      for(int o=1;o<16;o<<=1) p += __shfl_xor(p, o);
      float araw = lk(p + rn);
      float mnew = fmaxf(mx, araw);
      float sc = __expf(mx - mnew);
      float w  = __expf(araw - mnew);
      S = S*sc + w;
      #pragma unroll
      for(int c=0;c<8;c++) acc[c] = acc[c]*sc + w*b2f((unsigned short)xv[c]);
      mx = mnew;
    }
  }
  #pragma unroll
  for(int o=16;o<64;o<<=1){
    float mo = __shfl_xor(mx, o);
    float So = __shfl_xor(S, o);
    float mnew = fmaxf(mx, mo);
    float sa = __expf(mx - mnew), sb = __expf(mo - mnew);
    S = S*sa + So*sb;
    #pragma unroll
    for(int c=0;c<8;c++){
      float ao = __shfl_xor(acc[c], o);
      acc[c] = acc[c]*sa + ao*sb;
    }
    mx = mnew;
  }
  float inv = 1.f/(S + 1e-16f);
  if (grp == 0){
    #pragma unroll
    for(int c=0;c<8;c++)
      hout[(size_t)n*H + c0 + c] = eluf(acc[c]*inv + gbias[c0+c]);
  }
}

// ---------------- atom GATConv: single-pass online-softmax aggregation ----------------
__global__ __launch_bounds__(256) void k_atom_agg(
    const int* __restrict__ ei, const float* __restrict__ s1, const float* __restrict__ s2,
    const unsigned short* __restrict__ xl, const float* __restrict__ abias,
    const int* __restrict__ off, const int* __restrict__ perm,
    float* __restrict__ hout)
{
  int tid = threadIdx.x, wave = tid >> 6, lane = tid & 63;
  int grp = lane >> 4, sub = lane & 15;
  int n = blockIdx.x*4 + wave;
  if (n >= NND) return;
  int o0 = off[n], deg = off[n+1] - o0;
  int c0 = sub*8;
  float s2n = s2[n];
  float mx = -3.4e38f, S = 0.f;
  float acc[8] = {0,0,0,0,0,0,0,0};
  for(int base=0; base<deg; base+=64){
    int cnt = min(deg - base, 64);
    int s_l = 0; float ar_l = 0.f;
    if (lane < cnt){ int e = perm[o0 + base + lane]; s_l = ei[e]; ar_l = lk(s1[s_l] + s2n); }
    #pragma unroll 1
    for(int k=0;k<16;k++){
      int l = grp + k*4;
      if (l >= cnt) break;
      int s = __shfl(s_l, l);
      float araw = __shfl(ar_l, l);
      bf8 xv = *(const bf8*)(xl + (size_t)s*H + c0);
      float mnew = fmaxf(mx, araw);
      float sc = __expf(mx - mnew);
      float w  = __expf(araw - mnew);
      S = S*sc + w;
      #pragma unroll
      for(int c=0;c<8;c++) acc[c] = acc[c]*sc + w*b2f((unsigned short)xv[c]);
      mx = mnew;
    }
  }
  #pragma unroll
  for(int o=16;o<64;o<<=1){
    float mo = __shfl_xor(mx, o);
    float So = __shfl_xor(S, o);
    float mnew = fmaxf(mx, mo);
    float sa = __expf(mx - mnew), sb = __expf(mo - mnew);
    S = S*sa + So*sb;
    #pragma unroll
    for(int c=0;c<8;c++){
      float ao = __shfl_xor(acc[c], o);
      acc[c] = acc[c]*sa + ao*sb;
    }
    mx = mnew;
  }
  float inv = 1.f/(S + 1e-16f);
  if (grp == 0){
    #pragma unroll
    for(int c=0;c<8;c++)
      hout[(size_t)n*H + c0 + c] = eluf(acc[c]*inv + abias[c0+c]);
  }
}

// ---------------- graph readout: out0 = relu(segment_sum(xh)) ----------------
__global__ __launch_bounds__(256) void k_seg0(const float* __restrict__ xh, const int* __restrict__ goff,
                                              float* __restrict__ outg)
{
  int g = blockIdx.x*4 + (threadIdx.x >> 6);
  if (g >= NG) return;
  int lane = threadIdx.x & 63;
  int gs = goff[g], ge = goff[g+1];
  int h0 = lane*2;
  float a0 = 0.f, a1 = 0.f;
  for(int n=gs;n<ge;n++){
    const float* p = xh + (size_t)n*H + h0;
    a0 += p[0]; a1 += p[1];
  }
  outg[(size_t)g*H + h0]   = fmaxf(a0, 0.f);
  outg[(size_t)g*H + h0+1] = fmaxf(a1, 0.f);
}

// ---------------- molecule attention: single-pass online softmax (wave per graph) ----------------
__global__ __launch_bounds__(256) void k_mol_agg(const float* __restrict__ asrc, const float* __restrict__ d,
    const unsigned short* __restrict__ xm, const int* __restrict__ goff,
    const float* __restrict__ mbias, float* __restrict__ hmol)
{
  int tid = threadIdx.x, wave = tid >> 6, lane = tid & 63;
  int grp = lane >> 4, sub = lane & 15;
  int g = blockIdx.x*4 + wave;
  if (g >= NG) return;
  int gs = goff[g], num = goff[g+1] - gs;
  int c0 = sub*8;
  float dg = d[g];
  float mx = -3.4e38f, S = 0.f;
  float acc[8] = {0,0,0,0,0,0,0,0};
  for(int base=0; base<num; base+=64){
    int cnt = min(num - base, 64);
    float ar_l = 0.f;
    if (lane < cnt) ar_l = lk(asrc[gs + base + lane] + dg);
    #pragma unroll 1
    for(int k=0;k<16;k++){
      int l = grp + k*4;
      if (l >= cnt) break;
      float araw = __shfl(ar_l, l);
      int node = gs + base + l;
      bf8 xv = *(const bf8*)(xm + (size_t)node*H + c0);
      float mnew = fmaxf(mx, araw);
      float sc = __expf(mx - mnew);
      float w  = __expf(araw - mnew);
      S = S*sc + w;
      #pragma unroll
      for(int c=0;c<8;c++) acc[c] = acc[c]*sc + w*b2f((unsigned short)xv[c]);
      mx = mnew;
    }
  }
  #pragma unroll
  for(int o=16;o<64;o<<=1){
    float mo = __shfl_xor(mx, o);
    float So = __shfl_xor(S, o);
    float mnew = fmaxf(mx, mo);
    float sa = __expf(mx - mnew), sb = __expf(mo - mnew);
    S = S*sa + So*sb;
    #pragma unroll
    for(int c=0;c<8;c++){
      float ao = __shfl_xor(acc[c], o);
      acc[c] = acc[c]*sa + ao*sb;
    }
    mx = mnew;
  }
  float inv = 1.f/(S + 1e-16f);
  if (grp == 0){
    #pragma unroll
    for(int c=0;c<8;c++)
      hmol[(size_t)g*H + c0 + c] = eluf(acc[c]*inv + mbias[c0+c]);
  }
}

// ---------------- classifier head (wave per graph) -> FP32 output ----------------
__global__ __launch_bounds__(256) void k_cls(const float* __restrict__ emb,
   const float* __restrict__ W1, const float* __restrict__ b1,
   const float* __restrict__ W2, const float* __restrict__ b2,
   float* __restrict__ outp)
{
  __shared__ float W1t[H*64];   // [h][l]
  int tid = threadIdx.x;
  for(int i=tid;i<64*H;i+=256){
    int l = i >> 7, hh = i & 127;
    W1t[hh*64 + l] = W1[i];
  }
  __syncthreads();
  int wave = tid >> 6, lane = tid & 63;
  int g = blockIdx.x*4 + wave;
  if (g >= NG) return;
  const float* er = emb + (size_t)g*H;
  float acc = 0.f;
  for(int hh=0;hh<H;hh++) acc += er[hh] * W1t[hh*64 + lane];
  float hid = fmaxf(acc + b1[lane], 0.f);
  float p = hid * W2[lane];
  p = wsum(p);
  if (lane == 0) outp[g] = p + b2[0];
}

// =====================================================================================
extern "C" void kernel_launch(void* const* d_in, const int* in_sizes, int n_in,
                              void* d_out, int out_size, void* d_ws, size_t ws_size,
                              hipStream_t stream)
{
  const float* x      = (const float*)d_in[0];
  const float* eattr  = (const float*)d_in[1];
  const float* lin1W  = (const float*)d_in[2];
  const float* lin1b  = (const float*)d_in[3];
  const float* gcW    = (const float*)d_in[4];
  const float* gcatl  = (const float*)d_in[5];
  const float* gcatr  = (const float*)d_in[6];
  const float* gcW2   = (const float*)d_in[7];
  const float* gcb    = (const float*)d_in[8];
  const float* g0Wi   = (const float*)d_in[9];
  const float* g0Wh   = (const float*)d_in[10];
  const float* g0bi   = (const float*)d_in[11];
  const float* g0bh   = (const float*)d_in[12];
  const float* aW     = (const float*)d_in[13];
  const float* aas    = (const float*)d_in[14];
  const float* aad    = (const float*)d_in[15];
  const float* ab     = (const float*)d_in[16];
  const float* agWi   = (const float*)d_in[17];
  const float* agWh   = (const float*)d_in[18];
  const float* agbi   = (const float*)d_in[19];
  const float* agbh   = (const float*)d_in[20];
  const float* mW     = (const float*)d_in[21];
  const float* mas    = (const float*)d_in[22];
  const float* mad    = (const float*)d_in[23];
  const float* mb     = (const float*)d_in[24];
  const float* mgWi   = (const float*)d_in[25];
  const float* mgWh   = (const float*)d_in[26];
  const float* mgbi   = (const float*)d_in[27];
  const float* mgbh   = (const float*)d_in[28];
  const float* l2W    = (const float*)d_in[29];
  const float* l2b    = (const float*)d_in[30];
  const float* cW1    = (const float*)d_in[31];
  const float* cb1    = (const float*)d_in[32];
  const float* cW2    = (const float*)d_in[33];
  const float* cb2    = (const float*)d_in[34];
  const int* ei    = (const int*)d_in[35];
  const int* batch = (const int*)d_in[36];
  float* outp = (float*)d_out;

  char* p = (char*)d_ws;
  auto alloc = [&](size_t sz)->void*{ void* q = (void*)p; p += (sz + 511) & ~(size_t)511; return q; };
  float* x0            = (float*)alloc((size_t)NND*H*4);
  unsigned short* ux   = (unsigned short*)alloc((size_t)NND*256*2);  // interleaved u|x2 bf16
  unsigned short* bu   = (unsigned short*)alloc((size_t)NND*H*2);    // bf16 gather target (atom)
  float* xh            = (float*)alloc((size_t)NND*H*4);
  float* bh            = (float*)alloc((size_t)NND*H*4);
  unsigned short* xm   = (unsigned short*)x0;   // alias: x0 dead after first k_gru
  unsigned short* xp   = (unsigned short*)bh;   // alias: bh first written at k_gate_agg (lin1 reads xp before)
  // ---- zeroed block (fused-dot accumulators) ----
  char* z0 = p;
  float* rbuf          = (float*)alloc((size_t)NND*4);
  float* s1a           = (float*)alloc((size_t)NND*4);
  float* s2a           = (float*)alloc((size_t)NND*4);
  float* s1b           = (float*)alloc((size_t)NND*4);
  float* s2b           = (float*)alloc((size_t)NND*4);
  float* asrc          = (float*)alloc((size_t)NND*4);
  float* dg0           = (float*)alloc((size_t)NG*4);
  float* dg1           = (float*)alloc((size_t)NG*4);
  size_t zbytes = (size_t)(p - z0);
  // ----
  int* deg             = (int*)alloc((size_t)NND*4);
  int* off             = (int*)alloc((size_t)(NND+1)*4);
  int* cursor          = (int*)alloc((size_t)NND*4);
  int* perm            = (int*)alloc((size_t)NED*4);
  int* bsum            = (int*)alloc((size_t)(NBS+1)*4);
  int* goff            = (int*)alloc((size_t)(NG+1)*4);
  float* outg          = (float*)alloc((size_t)NG*H*4);
  float* hmol          = (float*)alloc((size_t)NG*H*4);
  float* om            = (float*)alloc((size_t)NG*H*4);
  float* emb           = (float*)alloc((size_t)NG*H*4);
  // fragment-ordered bf16 weights
  unsigned short* wp     = (unsigned short*)alloc((size_t)8*5*512*2);
  unsigned short* gcWnb  = (unsigned short*)alloc((size_t)H*H*2);
  unsigned short* gcW2b  = (unsigned short*)alloc((size_t)H*H*2);
  unsigned short* g0Wib  = (unsigned short*)alloc((size_t)3*H*H*2);
  unsigned short* g0Whb  = (unsigned short*)alloc((size_t)3*H*H*2);
  unsigned short* aWb    = (unsigned short*)alloc((size_t)2*H*H*2);
  unsigned short* agWib  = (unsigned short*)alloc((size_t)2*3*H*H*2);
  unsigned short* agWhb  = (unsigned short*)alloc((size_t)2*3*H*H*2);
  unsigned short* mWb    = (unsigned short*)alloc((size_t)H*H*2);
  unsigned short* l2Wb   = (unsigned short*)alloc((size_t)H*H*2);
  unsigned short* mgWib  = (unsigned short*)alloc((size_t)3*H*H*2);
  unsigned short* mgWhb  = (unsigned short*)alloc((size_t)3*H*H*2);

  const int HH = H*H, H3H = 3*H*H;
  k_wfrag<<<80 ,256,0,stream>>>(lin1W, FEAT, FEAT, wp, 8, 5);
  k_wfrag<<<64 ,256,0,stream>>>(gcW, H+EDIM, H, gcWnb, 8, 4);
  k_wfrag<<<64 ,256,0,stream>>>(gcW2, H, H, gcW2b, 8, 4);
  k_wfrag<<<192,256,0,stream>>>(g0Wi, H, H, g0Wib, 24, 4);
  k_wfrag<<<192,256,0,stream>>>(g0Wh, H, H, g0Whb, 24, 4);
  for(int l=0;l<2;l++){
    k_wfrag<<<64 ,256,0,stream>>>(aW + (size_t)l*HH, H, H, aWb + (size_t)l*HH, 8, 4);
    k_wfrag<<<192,256,0,stream>>>(agWi + (size_t)l*H3H, H, H, agWib + (size_t)l*H3H, 24, 4);
    k_wfrag<<<192,256,0,stream>>>(agWh + (size_t)l*H3H, H, H, agWhb + (size_t)l*H3H, 24, 4);
  }
  k_wfrag<<<64 ,256,0,stream>>>(mW, H, H, mWb, 8, 4);
  k_wfrag<<<64 ,256,0,stream>>>(l2W, H, H, l2Wb, 8, 4);
  k_wfrag<<<192,256,0,stream>>>(mgWi, H, H, mgWib, 24, 4);
  k_wfrag<<<192,256,0,stream>>>(mgWh, H, H, mgWhb, 24, 4);

  // zero dot accumulators + CSR degree
  hipMemsetAsync(z0, 0, zbytes, stream);
  hipMemsetAsync(deg, 0, (size_t)NND*4, stream);
  k_hist<<<1563,256,0,stream>>>(ei, deg);
  k_scan1<<<NBS,256,0,stream>>>(deg, off, bsum);
  k_scan2<<<1,512,0,stream>>>(bsum);
  k_scan3<<<NBS,256,0,stream>>>(off, bsum, cursor);
  k_scatter<<<1563,256,0,stream>>>(ei, cursor, perm);
  k_gstart<<<NBS,256,0,stream>>>(batch, goff);

  const int GB = (NND + 63)/64;
  // lin1 + leaky -> x0 fp32, fused dot rbuf = x0 . gcatr
  k_padx<<<25000,256,0,stream>>>(x, xp);
  k_gemm<5,4,true,true,1,false,1><<<GB,256,0,stream>>>(xp, FEATP, wp, lin1b, x0, NND,
                                                       gcatr, nullptr, rbuf, nullptr);
  // GATEConv: dual GEMM -> interleaved ux, then aggregation
  k_gemm2<<<GB,256,0,stream>>>(x0, gcWnb, gcW2b, ux, NND);
  k_gate_agg<<<25000,256,0,stream>>>(ei, eattr, gcW, gcatl, rbuf, ux, gcb, off, perm, bh);
  k_gru<<<NND/32,256,0,stream>>>(bh, x0, xh, g0Wib, g0Whb, g0bi, g0bh);

  // atom GAT layers (fused s1/s2 dots)
  float* s1l[2] = {s1a, s1b};
  float* s2l[2] = {s2a, s2b};
  for(int l=0;l<2;l++){
    k_gemm<4,4,false,false,0,true,2><<<GB,256,0,stream>>>(xh, H, aWb + (size_t)l*HH, nullptr, bu, NND,
                                                          aas + l*H, aad + l*H, s1l[l], s2l[l]);
    k_atom_agg<<<25000,256,0,stream>>>(ei, s1l[l], s2l[l], bu, ab + l*H, off, perm, bh);
    k_gru<<<NND/32,256,0,stream>>>(bh, xh, xh, agWib + (size_t)l*H3H, agWhb + (size_t)l*H3H,
                                   agbi + l*3*H, agbh + l*3*H);
  }

  // molecule readout (fused asrc dot)
  k_seg0<<<NG/4,256,0,stream>>>(xh, goff, outg);
  k_gemm<4,4,false,false,0,true,1><<<GB,256,0,stream>>>(xh, H, mWb, nullptr, xm, NND,
                                                        mas, nullptr, asrc, nullptr);
  float* dgt[2] = {dg0, dg1};
  for(int t=0;t<2;t++){
    k_gemm<4,4,false,false,0,false,1><<<(NG+63)/64,256,0,stream>>>(outg, H, mWb, nullptr, om, NG,
                                                                   mad, nullptr, dgt[t], nullptr);
    k_mol_agg<<<NG/4,256,0,stream>>>(asrc, dgt[t], xm, goff, mb, hmol);
    k_gru<<<NG/32,256,0,stream>>>(hmol, outg, outg, mgWib, mgWhb, mgbi, mgbh);
  }

  // head
  k_gemm<4,4,false,true,0,false,0><<<(NG+63)/64,256,0,stream>>>(outg, H, l2Wb, l2b, emb, NG,
                                                                nullptr, nullptr, nullptr, nullptr);
  k_cls<<<NG/4,256,0,stream>>>(emb, cW1, cb1, cW2, cb2, outp);
}

// Round 9
// 1091.506 us; speedup vs baseline: 1.0131x; 1.0131x over previous
//
#include <hip/hip_runtime.h>

#define NND 100000   // nodes
#define NED 400000   // edges
#define FEAT 143
#define FEATP 160
#define EDIM 6
#define H 128
#define NG 4096      // graphs
#define NBS 391      // ceil(NND/256)

typedef __attribute__((ext_vector_type(8))) short bf8;
typedef __attribute__((ext_vector_type(4))) float f4;

__device__ __forceinline__ float b2f(unsigned short u){
  unsigned int x = ((unsigned int)u) << 16;
  return __builtin_bit_cast(float, x);
}
__device__ __forceinline__ unsigned short f2b(float f){
  unsigned int u = __builtin_bit_cast(unsigned int, f);
  u = u + 0x7fffu + ((u >> 16) & 1u);   // RNE
  return (unsigned short)(u >> 16);
}
__device__ __forceinline__ float lk(float v){ return v >= 0.f ? v : 0.01f*v; }
__device__ __forceinline__ float eluf(float v){ return v > 0.f ? v : __expf(v) - 1.f; }
__device__ __forceinline__ float sgm(float v){ return 1.f/(1.f + __expf(-v)); }
__device__ __forceinline__ float wsum(float v){
  #pragma unroll
  for(int o=32;o>0;o>>=1) v += __shfl_xor(v,o);
  return v;
}
// 16B-aligned fp32x8 -> bf16x8
__device__ __forceinline__ bf8 cvt8(const float* p){
  f4 a = *(const f4*)p;
  f4 b = *(const f4*)(p+4);
  bf8 t;
  t[0]=(short)f2b(a[0]); t[1]=(short)f2b(a[1]); t[2]=(short)f2b(a[2]); t[3]=(short)f2b(a[3]);
  t[4]=(short)f2b(b[0]); t[5]=(short)f2b(b[1]); t[6]=(short)f2b(b[2]); t[7]=(short)f2b(b[3]);
  return t;
}

// ---------------- weight fp32 -> bf16 MFMA-fragment order ----------------
__global__ __launch_bounds__(256) void k_wfrag(const float* __restrict__ src, int lds, int srcK,
                                               unsigned short* __restrict__ dst, int NT, int KB){
  int i = blockIdx.x*256 + threadIdx.x;
  int total = NT*KB*512;
  if (i >= total) return;
  int j = i & 7, lane = (i>>3) & 63, kb = (i>>9) % KB, nt = i/(KB*512);
  int n = nt*16 + (lane & 15), k = kb*32 + (lane>>4)*8 + j;
  dst[i] = (k < srcK) ? f2b(src[(size_t)n*lds + k]) : (unsigned short)0;
}

// ---------------- CSR build (counting sort of edges by dst) ----------------
__global__ __launch_bounds__(256) void k_hist(const int* __restrict__ ei, int* __restrict__ deg){
  int e = blockIdx.x*256 + threadIdx.x;
  if (e < NED) atomicAdd(&deg[ei[NED + e]], 1);
}
__global__ __launch_bounds__(256) void k_scan1(const int* __restrict__ deg, int* __restrict__ off, int* __restrict__ bsum){
  __shared__ int s[256];
  int i = blockIdx.x*256 + threadIdx.x;
  int v = (i < NND) ? deg[i] : 0;
  s[threadIdx.x] = v; __syncthreads();
  for(int o=1;o<256;o<<=1){
    int t = 0; if (threadIdx.x >= o) t = s[threadIdx.x - o];
    __syncthreads(); s[threadIdx.x] += t; __syncthreads();
  }
  if (i < NND) off[i] = s[threadIdx.x] - v;
  if (threadIdx.x == 255) bsum[blockIdx.x] = s[255];
}
__global__ __launch_bounds__(512) void k_scan2(int* __restrict__ bsum){
  __shared__ int s[512];
  int t = threadIdx.x;
  int v = (t < NBS) ? bsum[t] : 0;
  s[t] = v; __syncthreads();
  for(int o=1;o<512;o<<=1){
    int x = 0; if (t >= o) x = s[t - o];
    __syncthreads(); s[t] += x; __syncthreads();
  }
  if (t < NBS) bsum[t] = s[t] - v;
  if (t == 511) bsum[NBS] = s[511];
}
__global__ __launch_bounds__(256) void k_scan3(int* __restrict__ off, const int* __restrict__ bsum, int* __restrict__ cursor){
  int i = blockIdx.x*256 + threadIdx.x;
  if (i < NND){
    int v = off[i] + bsum[blockIdx.x];
    off[i] = v; cursor[i] = v;
  }
  if (i == 0) off[NND] = bsum[NBS];
}
__global__ __launch_bounds__(256) void k_scatter(const int* __restrict__ ei, int* __restrict__ cursor, int* __restrict__ perm){
  int e = blockIdx.x*256 + threadIdx.x;
  if (e < NED){
    int p = atomicAdd(&cursor[ei[NED + e]], 1);
    perm[p] = e;
  }
}
__global__ __launch_bounds__(256) void k_gstart(const int* __restrict__ batch, int* __restrict__ goff){
  int i = blockIdx.x*256 + threadIdx.x;
  if (i >= NND) return;
  int bi = batch[i];
  int bp = (i > 0) ? batch[i-1] : -1;
  for(int g = bp+1; g <= bi; g++) goff[g] = i;
  if (i == NND-1) for(int g = bi+1; g <= NG; g++) goff[g] = NND;
}

// ---------------- pad + fp32->bf16 for lin1 A (K=143 -> 160) ----------------
__global__ __launch_bounds__(256) void k_padx(const float* __restrict__ x, unsigned short* __restrict__ xp){
  int r = blockIdx.x*4 + (threadIdx.x >> 6);
  int lane = threadIdx.x & 63;
  if (r >= NND) return;
  for(int i = lane; i < FEATP; i += 64)
    xp[(size_t)r*FEATP + i] = (i < FEAT) ? f2b(x[(size_t)r*FEAT + i]) : (unsigned short)0;
}

// ---------------- MFMA GEMM with optional fused row-dot epilogue ----------------
template<int KB, int RT, bool ABF16, bool BIAS, int ACT, bool OBF16, int DOT>
__global__ __launch_bounds__(256) void k_gemm(const void* __restrict__ Ap, int lda,
        const unsigned short* __restrict__ Wf,
        const float* __restrict__ bias, void* __restrict__ Cp, int M,
        const float* __restrict__ v1, const float* __restrict__ v2,
        float* __restrict__ o1, float* __restrict__ o2)
{
  int tid = threadIdx.x, wave = tid >> 6, lane = tid & 63;
  int m = lane & 15, quad = lane >> 4;
  int r0 = blockIdx.x * (16*RT);
  bf8 a[RT][KB];
  #pragma unroll
  for(int rt=0; rt<RT; rt++){
    int row = r0 + rt*16 + m;
    if (ABF16){
      const unsigned short* base = (const unsigned short*)Ap + (size_t)row*lda + quad*8;
      #pragma unroll
      for(int kb=0;kb<KB;kb++) a[rt][kb] = *(const bf8*)(base + kb*32);
    } else {
      const float* base = (const float*)Ap + (size_t)row*lda + quad*8;
      #pragma unroll
      for(int kb=0;kb<KB;kb++) a[rt][kb] = cvt8(base + kb*32);
    }
  }
  float d1[RT][4], d2[RT][4];
  if (DOT >= 1){
    #pragma unroll
    for(int rt=0;rt<RT;rt++)
      #pragma unroll
      for(int i=0;i<4;i++){ d1[rt][i] = 0.f; if (DOT==2) d2[rt][i] = 0.f; }
  }
  #pragma unroll
  for(int ct=0;ct<2;ct++){
    int nt = wave*2 + ct;
    int n = nt*16 + m;
    const bf8* wf = (const bf8*)Wf + (size_t)nt*KB*64;
    bf8 b[KB];
    #pragma unroll
    for(int kb=0;kb<KB;kb++) b[kb] = wf[kb*64 + lane];
    float bv = BIAS ? bias[n] : 0.f;
    float vv1 = (DOT>=1) ? v1[n] : 0.f;
    float vv2 = (DOT==2) ? v2[n] : 0.f;
    #pragma unroll
    for(int rt=0;rt<RT;rt++){
      f4 acc = {0.f,0.f,0.f,0.f};
      #pragma unroll
      for(int kb=0;kb<KB;kb++)
        acc = __builtin_amdgcn_mfma_f32_16x16x32_bf16(a[rt][kb], b[kb], acc, 0, 0, 0);
      #pragma unroll
      for(int i=0;i<4;i++){
        int row = r0 + rt*16 + quad*4 + i;
        float v = acc[i] + bv;
        if (ACT == 1) v = lk(v);
        if (DOT >= 1){ d1[rt][i] += v*vv1; if (DOT==2) d2[rt][i] += v*vv2; }
        if (row < M){
          if (OBF16) ((unsigned short*)Cp)[(size_t)row*H + n] = f2b(v);
          else       ((float*)Cp)[(size_t)row*H + n] = v;
        }
      }
    }
  }
  if (DOT >= 1){
    #pragma unroll
    for(int rt=0;rt<RT;rt++){
      #pragma unroll
      for(int i=0;i<4;i++){
        float dd = d1[rt][i];
        #pragma unroll
        for(int o=1;o<16;o<<=1) dd += __shfl_xor(dd, o);
        int row = r0 + rt*16 + quad*4 + i;
        if (m == 0 && row < M) atomicAdd(&o1[row], dd);
        if (DOT == 2){
          float ee = d2[rt][i];
          #pragma unroll
          for(int o=1;o<16;o<<=1) ee += __shfl_xor(ee, o);
          if (m == 0 && row < M) atomicAdd(&o2[row], ee);
        }
      }
    }
  }
}

// ---------------- dual GEMM for GATEConv: ux = interleave(A@W1^T, A@W2^T) bf16 ----------------
__global__ __launch_bounds__(256) void k_gemm2(const float* __restrict__ A,
        const unsigned short* __restrict__ Wf1, const unsigned short* __restrict__ Wf2,
        unsigned short* __restrict__ ux, int M)
{
  int tid = threadIdx.x, wave = tid >> 6, lane = tid & 63;
  int m = lane & 15, quad = lane >> 4;
  int r0 = blockIdx.x * 64;
  bf8 a[4][4];
  #pragma unroll
  for(int rt=0; rt<4; rt++){
    const float* base = A + (size_t)(r0 + rt*16 + m)*H + quad*8;
    #pragma unroll
    for(int kb=0;kb<4;kb++) a[rt][kb] = cvt8(base + kb*32);
  }
  #pragma unroll
  for(int ws=0; ws<2; ws++){
    const unsigned short* Wf = ws ? Wf2 : Wf1;
    #pragma unroll
    for(int ct=0;ct<2;ct++){
      int nt = wave*2 + ct;
      int n = nt*16 + m;
      const bf8* wf = (const bf8*)Wf + (size_t)nt*256;
      bf8 b[4];
      #pragma unroll
      for(int kb=0;kb<4;kb++) b[kb] = wf[kb*64 + lane];
      int pos = (n>>3)*16 + ws*8 + (n&7);
      #pragma unroll
      for(int rt=0;rt<4;rt++){
        f4 acc = {0.f,0.f,0.f,0.f};
        #pragma unroll
        for(int kb=0;kb<4;kb++)
          acc = __builtin_amdgcn_mfma_f32_16x16x32_bf16(a[rt][kb], b[kb], acc, 0, 0, 0);
        #pragma unroll
        for(int i=0;i<4;i++){
          int row = r0 + rt*16 + quad*4 + i;
          if (row < M) ux[(size_t)row*256 + pos] = f2b(acc[i]);
        }
      }
    }
  }
}

// ---------------- fused MFMA GRU v4 (fragment-ordered weights, 32 rows/block) ----------------
__global__ __launch_bounds__(256) void k_gru(const float* __restrict__ Xin,
      const float* __restrict__ Hid, float* __restrict__ Out,
      const unsigned short* __restrict__ Wif, const unsigned short* __restrict__ Whf,
      const float* __restrict__ bi, const float* __restrict__ bh_)
{
  int tid = threadIdx.x, wave = tid >> 6, lane = tid & 63;
  int m = lane & 15, quad = lane >> 4;
  int r0 = blockIdx.x * 32;
  bf8 ax[2][4], ah[2][4];
  #pragma unroll
  for(int rt=0;rt<2;rt++){
    const float* xb = Xin + (size_t)(r0+rt*16+m)*H + quad*8;
    const float* hb = Hid + (size_t)(r0+rt*16+m)*H + quad*8;
    #pragma unroll
    for(int kb=0;kb<4;kb++){
      ax[rt][kb] = cvt8(xb + kb*32);
      ah[rt][kb] = cvt8(hb + kb*32);
    }
  }
  __syncthreads();   // all A-frag reads of (possibly aliased) Hid done before any store
  f4 rg[2][2], ng[2][2];
  #pragma unroll
  for(int c=0;c<2;c++){
    int nt = wave*2 + c;
    const bf8* wi = (const bf8*)Wif + (size_t)nt*256;
    const bf8* wh = (const bf8*)Whf + (size_t)nt*256;
    int col = nt*16 + m;
    float bb = bi[col] + bh_[col];
    #pragma unroll
    for(int rt=0;rt<2;rt++){
      f4 acc = {0.f,0.f,0.f,0.f};
      #pragma unroll
      for(int kb=0;kb<4;kb++){
        acc = __builtin_amdgcn_mfma_f32_16x16x32_bf16(ax[rt][kb], wi[kb*64+lane], acc,0,0,0);
        acc = __builtin_amdgcn_mfma_f32_16x16x32_bf16(ah[rt][kb], wh[kb*64+lane], acc,0,0,0);
      }
      #pragma unroll
      for(int i=0;i<4;i++) rg[c][rt][i] = sgm(acc[i] + bb);
    }
  }
  #pragma unroll
  for(int c=0;c<2;c++){
    int nt = 16 + wave*2 + c;
    const bf8* wi = (const bf8*)Wif + (size_t)nt*256;
    const bf8* wh = (const bf8*)Whf + (size_t)nt*256;
    int col = (wave*2+c)*16 + m;
    float bin_ = bi[col+256], bhn_ = bh_[col+256];
    #pragma unroll
    for(int rt=0;rt<2;rt++){
      f4 a1 = {0.f,0.f,0.f,0.f}, a2 = {0.f,0.f,0.f,0.f};
      #pragma unroll
      for(int kb=0;kb<4;kb++){
        a1 = __builtin_amdgcn_mfma_f32_16x16x32_bf16(ax[rt][kb], wi[kb*64+lane], a1,0,0,0);
        a2 = __builtin_amdgcn_mfma_f32_16x16x32_bf16(ah[rt][kb], wh[kb*64+lane], a2,0,0,0);
      }
      #pragma unroll
      for(int i=0;i<4;i++)
        ng[c][rt][i] = tanhf(a1[i] + bin_ + rg[c][rt][i]*(a2[i] + bhn_));
    }
  }
  #pragma unroll
  for(int c=0;c<2;c++){
    int nt = 8 + wave*2 + c;
    const bf8* wi = (const bf8*)Wif + (size_t)nt*256;
    const bf8* wh = (const bf8*)Whf + (size_t)nt*256;
    int col = (wave*2+c)*16 + m;
    float bb = bi[col+128] + bh_[col+128];
    #pragma unroll
    for(int rt=0;rt<2;rt++){
      f4 acc = {0.f,0.f,0.f,0.f};
      #pragma unroll
      for(int kb=0;kb<4;kb++){
        acc = __builtin_amdgcn_mfma_f32_16x16x32_bf16(ax[rt][kb], wi[kb*64+lane], acc,0,0,0);
        acc = __builtin_amdgcn_mfma_f32_16x16x32_bf16(ah[rt][kb], wh[kb*64+lane], acc,0,0,0);
      }
      #pragma unroll
      for(int i=0;i<4;i++){
        float zg = sgm(acc[i] + bb);
        int row = r0 + rt*16 + quad*4 + i;
        float hv = Hid[(size_t)row*H + col];
        float o = (1.f - zg)*ng[c][rt][i] + zg*hv;
        Out[(size_t)row*H + col] = fmaxf(o, 0.f);
      }
    }
  }
}

// ---------------- GATEConv: online-softmax aggregation, reg W1e (128 VGPR budget) ----------------
// __launch_bounds__(256,4): allow 128 VGPRs so W1e[48] stays in registers (r8 spilled at 64).
__global__ __launch_bounds__(256, 4) void k_gate_agg(
   const int* __restrict__ ei, const float* __restrict__ eattr,
   const float* __restrict__ gcW, const float* __restrict__ attl,
   const float* __restrict__ r, const unsigned short* __restrict__ ux,
   const float* __restrict__ gbias,
   const int* __restrict__ off, const int* __restrict__ perm,
   float* __restrict__ hout)
{
  int tid = threadIdx.x;
  int wave = tid >> 6, lane = tid & 63;
  int grp = lane >> 4, sub = lane & 15;
  int n = blockIdx.x*4 + wave;
  if (n >= NND) return;
  int c0 = sub*8;
  float W1e[48];        // edge-linear weights for this lane's 8 cols
  #pragma unroll
  for(int c=0;c<8;c++)
    #pragma unroll
    for(int j=0;j<EDIM;j++)
      W1e[c*EDIM+j] = gcW[(size_t)(c0+c)*(H+EDIM) + H + j];
  float attl8[8];
  #pragma unroll
  for(int c=0;c<8;c++) attl8[c] = attl[c0+c];
  int o0 = off[n], deg = off[n+1] - o0;
  float rn = r[n];
  float mx = -3.4e38f, S = 0.f;
  float acc[8] = {0,0,0,0,0,0,0,0};
  for(int base=0; base<deg; base+=64){
    int cnt = min(deg - base, 64);
    int s_l = 0;
    float ea_l[EDIM] = {0,0,0,0,0,0};
    if (lane < cnt){
      int e = perm[o0 + base + lane];
      s_l = ei[e];
      const float* ep = eattr + (size_t)e*EDIM;
      #pragma unroll
      for(int j=0;j<EDIM;j++) ea_l[j] = ep[j];
    }
    #pragma unroll 1
    for(int k=0;k<16;k++){
      int l = grp + k*4;
      if (l >= cnt) break;
      int s = __shfl(s_l, l);
      float ea[EDIM];
      #pragma unroll
      for(int j=0;j<EDIM;j++) ea[j] = __shfl(ea_l[j], l);
      const unsigned short* rowp = ux + (size_t)s*256 + sub*16;
      bf8 uv = *(const bf8*)rowp;
      bf8 xv = *(const bf8*)(rowp + 8);
      float p = 0.f;
      #pragma unroll
      for(int c=0;c<8;c++){
        float ve = 0.f;
        #pragma unroll
        for(int j=0;j<EDIM;j++) ve += ea[j] * W1e[c*EDIM + j];
        float t = lk(b2f((unsigned short)uv[c]) + ve);
        p += t * attl8[c];
      }
      #pragma unroll
      for(int o=1;o<16;o<<=1) p += __shfl_xor(p, o);
      float araw = lk(p + rn);
      float mnew = fmaxf(mx, araw);
      float sc = __expf(mx - mnew);
      float w  = __expf(araw - mnew);
      S = S*sc + w;
      #pragma unroll
      for(int c=0;c<8;c++) acc[c] = acc[c]*sc + w*b2f((unsigned short)xv[c]);
      mx = mnew;
    }
  }
  #pragma unroll
  for(int o=16;o<64;o<<=1){
    float mo = __shfl_xor(mx, o);
    float So = __shfl_xor(S, o);
    float mnew = fmaxf(mx, mo);
    float sa = __expf(mx - mnew), sb = __expf(mo - mnew);
    S = S*sa + So*sb;
    #pragma unroll
    for(int c=0;c<8;c++){
      float ao = __shfl_xor(acc[c], o);
      acc[c] = acc[c]*sa + ao*sb;
    }
    mx = mnew;
  }
  float inv = 1.f/(S + 1e-16f);
  if (grp == 0){
    #pragma unroll
    for(int c=0;c<8;c++)
      hout[(size_t)n*H + c0 + c] = eluf(acc[c]*inv + gbias[c0+c]);
  }
}

// ---------------- atom GATConv: single-pass online-softmax aggregation ----------------
__global__ __launch_bounds__(256) void k_atom_agg(
    const int* __restrict__ ei, const float* __restrict__ s1, const float* __restrict__ s2,
    const unsigned short* __restrict__ xl, const float* __restrict__ abias,
    const int* __restrict__ off, const int* __restrict__ perm,
    float* __restrict__ hout)
{
  int tid = threadIdx.x, wave = tid >> 6, lane = tid & 63;
  int grp = lane >> 4, sub = lane & 15;
  int n = blockIdx.x*4 + wave;
  if (n >= NND) return;
  int o0 = off[n], deg = off[n+1] - o0;
  int c0 = sub*8;
  float s2n = s2[n];
  float mx = -3.4e38f, S = 0.f;
  float acc[8] = {0,0,0,0,0,0,0,0};
  for(int base=0; base<deg; base+=64){
    int cnt = min(deg - base, 64);
    int s_l = 0; float ar_l = 0.f;
    if (lane < cnt){ int e = perm[o0 + base + lane]; s_l = ei[e]; ar_l = lk(s1[s_l] + s2n); }
    #pragma unroll 1
    for(int k=0;k<16;k++){
      int l = grp + k*4;
      if (l >= cnt) break;
      int s = __shfl(s_l, l);
      float araw = __shfl(ar_l, l);
      bf8 xv = *(const bf8*)(xl + (size_t)s*H + c0);
      float mnew = fmaxf(mx, araw);
      float sc = __expf(mx - mnew);
      float w  = __expf(araw - mnew);
      S = S*sc + w;
      #pragma unroll
      for(int c=0;c<8;c++) acc[c] = acc[c]*sc + w*b2f((unsigned short)xv[c]);
      mx = mnew;
    }
  }
  #pragma unroll
  for(int o=16;o<64;o<<=1){
    float mo = __shfl_xor(mx, o);
    float So = __shfl_xor(S, o);
    float mnew = fmaxf(mx, mo);
    float sa = __expf(mx - mnew), sb = __expf(mo - mnew);
    S = S*sa + So*sb;
    #pragma unroll
    for(int c=0;c<8;c++){
      float ao = __shfl_xor(acc[c], o);
      acc[c] = acc[c]*sa + ao*sb;
    }
    mx = mnew;
  }
  float inv = 1.f/(S + 1e-16f);
  if (grp == 0){
    #pragma unroll
    for(int c=0;c<8;c++)
      hout[(size_t)n*H + c0 + c] = eluf(acc[c]*inv + abias[c0+c]);
  }
}

// ---------------- graph readout: out0 = relu(segment_sum(xh)) ----------------
__global__ __launch_bounds__(256) void k_seg0(const float* __restrict__ xh, const int* __restrict__ goff,
                                              float* __restrict__ outg)
{
  int g = blockIdx.x*4 + (threadIdx.x >> 6);
  if (g >= NG) return;
  int lane = threadIdx.x & 63;
  int gs = goff[g], ge = goff[g+1];
  int h0 = lane*2;
  float a0 = 0.f, a1 = 0.f;
  for(int n=gs;n<ge;n++){
    const float* p = xh + (size_t)n*H + h0;
    a0 += p[0]; a1 += p[1];
  }
  outg[(size_t)g*H + h0]   = fmaxf(a0, 0.f);
  outg[(size_t)g*H + h0+1] = fmaxf(a1, 0.f);
}

// ---------------- molecule attention: single-pass online softmax (wave per graph) ----------------
__global__ __launch_bounds__(256) void k_mol_agg(const float* __restrict__ asrc, const float* __restrict__ d,
    const unsigned short* __restrict__ xm, const int* __restrict__ goff,
    const float* __restrict__ mbias, float* __restrict__ hmol)
{
  int tid = threadIdx.x, wave = tid >> 6, lane = tid & 63;
  int grp = lane >> 4, sub = lane & 15;
  int g = blockIdx.x*4 + wave;
  if (g >= NG) return;
  int gs = goff[g], num = goff[g+1] - gs;
  int c0 = sub*8;
  float dg = d[g];
  float mx = -3.4e38f, S = 0.f;
  float acc[8] = {0,0,0,0,0,0,0,0};
  for(int base=0; base<num; base+=64){
    int cnt = min(num - base, 64);
    float ar_l = 0.f;
    if (lane < cnt) ar_l = lk(asrc[gs + base + lane] + dg);
    #pragma unroll 1
    for(int k=0;k<16;k++){
      int l = grp + k*4;
      if (l >= cnt) break;
      float araw = __shfl(ar_l, l);
      int node = gs + base + l;
      bf8 xv = *(const bf8*)(xm + (size_t)node*H + c0);
      float mnew = fmaxf(mx, araw);
      float sc = __expf(mx - mnew);
      float w  = __expf(araw - mnew);
      S = S*sc + w;
      #pragma unroll
      for(int c=0;c<8;c++) acc[c] = acc[c]*sc + w*b2f((unsigned short)xv[c]);
      mx = mnew;
    }
  }
  #pragma unroll
  for(int o=16;o<64;o<<=1){
    float mo = __shfl_xor(mx, o);
    float So = __shfl_xor(S, o);
    float mnew = fmaxf(mx, mo);
    float sa = __expf(mx - mnew), sb = __expf(mo - mnew);
    S = S*sa + So*sb;
    #pragma unroll
    for(int c=0;c<8;c++){
      float ao = __shfl_xor(acc[c], o);
      acc[c] = acc[c]*sa + ao*sb;
    }
    mx = mnew;
  }
  float inv = 1.f/(S + 1e-16f);
  if (grp == 0){
    #pragma unroll
    for(int c=0;c<8;c++)
      hmol[(size_t)g*H + c0 + c] = eluf(acc[c]*inv + mbias[c0+c]);
  }
}

// ---------------- classifier head (wave per graph) -> FP32 output ----------------
__global__ __launch_bounds__(256) void k_cls(const float* __restrict__ emb,
   const float* __restrict__ W1, const float* __restrict__ b1,
   const float* __restrict__ W2, const float* __restrict__ b2,
   float* __restrict__ outp)
{
  __shared__ float W1t[H*64];   // [h][l]
  int tid = threadIdx.x;
  for(int i=tid;i<64*H;i+=256){
    int l = i >> 7, hh = i & 127;
    W1t[hh*64 + l] = W1[i];
  }
  __syncthreads();
  int wave = tid >> 6, lane = tid & 63;
  int g = blockIdx.x*4 + wave;
  if (g >= NG) return;
  const float* er = emb + (size_t)g*H;
  float acc = 0.f;
  for(int hh=0;hh<H;hh++) acc += er[hh] * W1t[hh*64 + lane];
  float hid = fmaxf(acc + b1[lane], 0.f);
  float p = hid * W2[lane];
  p = wsum(p);
  if (lane == 0) outp[g] = p + b2[0];
}

// =====================================================================================
extern "C" void kernel_launch(void* const* d_in, const int* in_sizes, int n_in,
                              void* d_out, int out_size, void* d_ws, size_t ws_size,
                              hipStream_t stream)
{
  const float* x      = (const float*)d_in[0];
  const float* eattr  = (const float*)d_in[1];
  const float* lin1W  = (const float*)d_in[2];
  const float* lin1b  = (const float*)d_in[3];
  const float* gcW    = (const float*)d_in[4];
  const float* gcatl  = (const float*)d_in[5];
  const float* gcatr  = (const float*)d_in[6];
  const float* gcW2   = (const float*)d_in[7];
  const float* gcb    = (const float*)d_in[8];
  const float* g0Wi   = (const float*)d_in[9];
  const float* g0Wh   = (const float*)d_in[10];
  const float* g0bi   = (const float*)d_in[11];
  const float* g0bh   = (const float*)d_in[12];
  const float* aW     = (const float*)d_in[13];
  const float* aas    = (const float*)d_in[14];
  const float* aad    = (const float*)d_in[15];
  const float* ab     = (const float*)d_in[16];
  const float* agWi   = (const float*)d_in[17];
  const float* agWh   = (const float*)d_in[18];
  const float* agbi   = (const float*)d_in[19];
  const float* agbh   = (const float*)d_in[20];
  const float* mW     = (const float*)d_in[21];
  const float* mas    = (const float*)d_in[22];
  const float* mad    = (const float*)d_in[23];
  const float* mb     = (const float*)d_in[24];
  const float* mgWi   = (const float*)d_in[25];
  const float* mgWh   = (const float*)d_in[26];
  const float* mgbi   = (const float*)d_in[27];
  const float* mgbh   = (const float*)d_in[28];
  const float* l2W    = (const float*)d_in[29];
  const float* l2b    = (const float*)d_in[30];
  const float* cW1    = (const float*)d_in[31];
  const float* cb1    = (const float*)d_in[32];
  const float* cW2    = (const float*)d_in[33];
  const float* cb2    = (const float*)d_in[34];
  const int* ei    = (const int*)d_in[35];
  const int* batch = (const int*)d_in[36];
  float* outp = (float*)d_out;

  char* p = (char*)d_ws;
  auto alloc = [&](size_t sz)->void*{ void* q = (void*)p; p += (sz + 511) & ~(size_t)511; return q; };
  float* x0            = (float*)alloc((size_t)NND*H*4);
  unsigned short* ux   = (unsigned short*)alloc((size_t)NND*256*2);  // interleaved u|x2 bf16
  unsigned short* bu   = (unsigned short*)alloc((size_t)NND*H*2);    // bf16 gather target (atom)
  float* xh            = (float*)alloc((size_t)NND*H*4);
  float* bh            = (float*)alloc((size_t)NND*H*4);
  unsigned short* xm   = (unsigned short*)x0;   // alias: x0 dead after first k_gru
  unsigned short* xp   = (unsigned short*)bh;   // alias: bh first written at k_gate_agg (lin1 reads xp before)
  // ---- zeroed block (fused-dot accumulators) ----
  char* z0 = p;
  float* rbuf          = (float*)alloc((size_t)NND*4);
  float* s1a           = (float*)alloc((size_t)NND*4);
  float* s2a           = (float*)alloc((size_t)NND*4);
  float* s1b           = (float*)alloc((size_t)NND*4);
  float* s2b           = (float*)alloc((size_t)NND*4);
  float* asrc          = (float*)alloc((size_t)NND*4);
  float* dg0           = (float*)alloc((size_t)NG*4);
  float* dg1           = (float*)alloc((size_t)NG*4);
  size_t zbytes = (size_t)(p - z0);
  // ----
  int* deg             = (int*)alloc((size_t)NND*4);
  int* off             = (int*)alloc((size_t)(NND+1)*4);
  int* cursor          = (int*)alloc((size_t)NND*4);
  int* perm            = (int*)alloc((size_t)NED*4);
  int* bsum            = (int*)alloc((size_t)(NBS+1)*4);
  int* goff            = (int*)alloc((size_t)(NG+1)*4);
  float* outg          = (float*)alloc((size_t)NG*H*4);
  float* hmol          = (float*)alloc((size_t)NG*H*4);
  float* om            = (float*)alloc((size_t)NG*H*4);
  float* emb           = (float*)alloc((size_t)NG*H*4);
  // fragment-ordered bf16 weights
  unsigned short* wp     = (unsigned short*)alloc((size_t)8*5*512*2);
  unsigned short* gcWnb  = (unsigned short*)alloc((size_t)H*H*2);
  unsigned short* gcW2b  = (unsigned short*)alloc((size_t)H*H*2);
  unsigned short* g0Wib  = (unsigned short*)alloc((size_t)3*H*H*2);
  unsigned short* g0Whb  = (unsigned short*)alloc((size_t)3*H*H*2);
  unsigned short* aWb    = (unsigned short*)alloc((size_t)2*H*H*2);
  unsigned short* agWib  = (unsigned short*)alloc((size_t)2*3*H*H*2);
  unsigned short* agWhb  = (unsigned short*)alloc((size_t)2*3*H*H*2);
  unsigned short* mWb    = (unsigned short*)alloc((size_t)H*H*2);
  unsigned short* l2Wb   = (unsigned short*)alloc((size_t)H*H*2);
  unsigned short* mgWib  = (unsigned short*)alloc((size_t)3*H*H*2);
  unsigned short* mgWhb  = (unsigned short*)alloc((size_t)3*H*H*2);

  const int HH = H*H, H3H = 3*H*H;
  k_wfrag<<<80 ,256,0,stream>>>(lin1W, FEAT, FEAT, wp, 8, 5);
  k_wfrag<<<64 ,256,0,stream>>>(gcW, H+EDIM, H, gcWnb, 8, 4);
  k_wfrag<<<64 ,256,0,stream>>>(gcW2, H, H, gcW2b, 8, 4);
  k_wfrag<<<192,256,0,stream>>>(g0Wi, H, H, g0Wib, 24, 4);
  k_wfrag<<<192,256,0,stream>>>(g0Wh, H, H, g0Whb, 24, 4);
  for(int l=0;l<2;l++){
    k_wfrag<<<64 ,256,0,stream>>>(aW + (size_t)l*HH, H, H, aWb + (size_t)l*HH, 8, 4);
    k_wfrag<<<192,256,0,stream>>>(agWi + (size_t)l*H3H, H, H, agWib + (size_t)l*H3H, 24, 4);
    k_wfrag<<<192,256,0,stream>>>(agWh + (size_t)l*H3H, H, H, agWhb + (size_t)l*H3H, 24, 4);
  }
  k_wfrag<<<64 ,256,0,stream>>>(mW, H, H, mWb, 8, 4);
  k_wfrag<<<64 ,256,0,stream>>>(l2W, H, H, l2Wb, 8, 4);
  k_wfrag<<<192,256,0,stream>>>(mgWi, H, H, mgWib, 24, 4);
  k_wfrag<<<192,256,0,stream>>>(mgWh, H, H, mgWhb, 24, 4);

  // zero dot accumulators + CSR degree
  hipMemsetAsync(z0, 0, zbytes, stream);
  hipMemsetAsync(deg, 0, (size_t)NND*4, stream);
  k_hist<<<1563,256,0,stream>>>(ei, deg);
  k_scan1<<<NBS,256,0,stream>>>(deg, off, bsum);
  k_scan2<<<1,512,0,stream>>>(bsum);
  k_scan3<<<NBS,256,0,stream>>>(off, bsum, cursor);
  k_scatter<<<1563,256,0,stream>>>(ei, cursor, perm);
  k_gstart<<<NBS,256,0,stream>>>(batch, goff);

  const int GB = (NND + 63)/64;
  // lin1 + leaky -> x0 fp32, fused dot rbuf = x0 . gcatr
  k_padx<<<25000,256,0,stream>>>(x, xp);
  k_gemm<5,4,true,true,1,false,1><<<GB,256,0,stream>>>(xp, FEATP, wp, lin1b, x0, NND,
                                                       gcatr, nullptr, rbuf, nullptr);
  // GATEConv: dual GEMM -> interleaved ux, then aggregation
  k_gemm2<<<GB,256,0,stream>>>(x0, gcWnb, gcW2b, ux, NND);
  k_gate_agg<<<25000,256,0,stream>>>(ei, eattr, gcW, gcatl, rbuf, ux, gcb, off, perm, bh);
  k_gru<<<NND/32,256,0,stream>>>(bh, x0, xh, g0Wib, g0Whb, g0bi, g0bh);

  // atom GAT layers (fused s1/s2 dots)
  float* s1l[2] = {s1a, s1b};
  float* s2l[2] = {s2a, s2b};
  for(int l=0;l<2;l++){
    k_gemm<4,4,false,false,0,true,2><<<GB,256,0,stream>>>(xh, H, aWb + (size_t)l*HH, nullptr, bu, NND,
                                                          aas + l*H, aad + l*H, s1l[l], s2l[l]);
    k_atom_agg<<<25000,256,0,stream>>>(ei, s1l[l], s2l[l], bu, ab + l*H, off, perm, bh);
    k_gru<<<NND/32,256,0,stream>>>(bh, xh, xh, agWib + (size_t)l*H3H, agWhb + (size_t)l*H3H,
                                   agbi + l*3*H, agbh + l*3*H);
  }

  // molecule readout (fused asrc dot)
  k_seg0<<<NG/4,256,0,stream>>>(xh, goff, outg);
  k_gemm<4,4,false,false,0,true,1><<<GB,256,0,stream>>>(xh, H, mWb, nullptr, xm, NND,
                                                        mas, nullptr, asrc, nullptr);
  float* dgt[2] = {dg0, dg1};
  for(int t=0;t<2;t++){
    k_gemm<4,4,false,false,0,false,1><<<(NG+63)/64,256,0,stream>>>(outg, H, mWb, nullptr, om, NG,
                                                                   mad, nullptr, dgt[t], nullptr);
    k_mol_agg<<<NG/4,256,0,stream>>>(asrc, dgt[t], xm, goff, mb, hmol);
    k_gru<<<NG/32,256,0,stream>>>(hmol, outg, outg, mgWib, mgWhb, mgbi, mgbh);
  }

  // head
  k_gemm<4,4,false,true,0,false,0><<<(NG+63)/64,256,0,stream>>>(outg, H, l2Wb, l2b, emb, NG,
                                                                nullptr, nullptr, nullptr, nullptr);
  k_cls<<<NG/4,256,0,stream>>>(emb, cW1, cb1, cW2, cb2, outp);
}

// Round 10
// 1057.052 us; speedup vs baseline: 1.0461x; 1.0326x over previous
//
#include <hip/hip_runtime.h>

#define NND 100000   // nodes
#define NED 400000   // edges
#define FEAT 143
#define FEATP 160
#define EDIM 6
#define H 128
#define NG 4096      // graphs
#define NBS 391      // ceil(NND/256)

typedef __attribute__((ext_vector_type(8))) short bf8;
typedef __attribute__((ext_vector_type(4))) float f4;

__device__ __forceinline__ float b2f(unsigned short u){
  unsigned int x = ((unsigned int)u) << 16;
  return __builtin_bit_cast(float, x);
}
__device__ __forceinline__ unsigned short f2b(float f){
  unsigned int u = __builtin_bit_cast(unsigned int, f);
  u = u + 0x7fffu + ((u >> 16) & 1u);   // RNE
  return (unsigned short)(u >> 16);
}
__device__ __forceinline__ float lk(float v){ return v >= 0.f ? v : 0.01f*v; }
__device__ __forceinline__ float eluf(float v){ return v > 0.f ? v : __expf(v) - 1.f; }
__device__ __forceinline__ float sgm(float v){ return 1.f/(1.f + __expf(-v)); }
__device__ __forceinline__ float wsum(float v){
  #pragma unroll
  for(int o=32;o>0;o>>=1) v += __shfl_xor(v,o);
  return v;
}
// 16B-aligned fp32x8 -> bf16x8
__device__ __forceinline__ bf8 cvt8(const float* p){
  f4 a = *(const f4*)p;
  f4 b = *(const f4*)(p+4);
  bf8 t;
  t[0]=(short)f2b(a[0]); t[1]=(short)f2b(a[1]); t[2]=(short)f2b(a[2]); t[3]=(short)f2b(a[3]);
  t[4]=(short)f2b(b[0]); t[5]=(short)f2b(b[1]); t[6]=(short)f2b(b[2]); t[7]=(short)f2b(b[3]);
  return t;
}

// ---------------- batched weight fp32 -> bf16 MFMA-fragment order ----------------
struct WDesc { const float* src; unsigned short* dst; int lds, srcK, NT, KB; };
struct WPack { WDesc d[17]; int nd; };
#define WBLK 192   // blocks per descriptor (covers NT*KB*512 <= 49152)
__global__ __launch_bounds__(256) void k_wfrag_all(WPack P){
  int di = blockIdx.x / WBLK;
  if (di >= P.nd) return;
  WDesc w = P.d[di];
  int total = w.NT*w.KB*512;
  int i = (blockIdx.x % WBLK)*256 + threadIdx.x;
  if (i >= total) return;
  int j = i & 7, lane = (i>>3) & 63, kb = (i>>9) % w.KB, nt = i/(w.KB*512);
  int n = nt*16 + (lane & 15), k = kb*32 + (lane>>4)*8 + j;
  w.dst[i] = (k < w.srcK) ? f2b(w.src[(size_t)n*w.lds + k]) : (unsigned short)0;
}

// ---------------- CSR build (counting sort of edges by dst, with payloads) ----------------
__global__ __launch_bounds__(256) void k_hist(const int* __restrict__ ei, int* __restrict__ deg){
  int e = blockIdx.x*256 + threadIdx.x;
  if (e < NED) atomicAdd(&deg[ei[NED + e]], 1);
}
__global__ __launch_bounds__(256) void k_scan1(const int* __restrict__ deg, int* __restrict__ off, int* __restrict__ bsum){
  __shared__ int s[256];
  int i = blockIdx.x*256 + threadIdx.x;
  int v = (i < NND) ? deg[i] : 0;
  s[threadIdx.x] = v; __syncthreads();
  for(int o=1;o<256;o<<=1){
    int t = 0; if (threadIdx.x >= o) t = s[threadIdx.x - o];
    __syncthreads(); s[threadIdx.x] += t; __syncthreads();
  }
  if (i < NND) off[i] = s[threadIdx.x] - v;
  if (threadIdx.x == 255) bsum[blockIdx.x] = s[255];
}
__global__ __launch_bounds__(512) void k_scan2(int* __restrict__ bsum){
  __shared__ int s[512];
  int t = threadIdx.x;
  int v = (t < NBS) ? bsum[t] : 0;
  s[t] = v; __syncthreads();
  for(int o=1;o<512;o<<=1){
    int x = 0; if (t >= o) x = s[t - o];
    __syncthreads(); s[t] += x; __syncthreads();
  }
  if (t < NBS) bsum[t] = s[t] - v;
  if (t == 511) bsum[NBS] = s[511];
}
__global__ __launch_bounds__(256) void k_scan3(int* __restrict__ off, const int* __restrict__ bsum, int* __restrict__ cursor){
  int i = blockIdx.x*256 + threadIdx.x;
  if (i < NND){
    int v = off[i] + bsum[blockIdx.x];
    off[i] = v; cursor[i] = v;
  }
  if (i == 0) off[NND] = bsum[NBS];
}
// scatter edge payloads directly into dst-sorted order: srcs (src node id) + ea_srt (edge attrs)
__global__ __launch_bounds__(256) void k_scatter(const int* __restrict__ ei, const float* __restrict__ eattr,
                                                 int* __restrict__ cursor,
                                                 int* __restrict__ srcs, float* __restrict__ ea_srt){
  int e = blockIdx.x*256 + threadIdx.x;
  if (e < NED){
    int p = atomicAdd(&cursor[ei[NED + e]], 1);
    srcs[p] = ei[e];
    const float* ep = eattr + (size_t)e*EDIM;
    float* dp = ea_srt + (size_t)p*EDIM;
    #pragma unroll
    for(int j=0;j<EDIM;j++) dp[j] = ep[j];
  }
}
__global__ __launch_bounds__(256) void k_gstart(const int* __restrict__ batch, int* __restrict__ goff){
  int i = blockIdx.x*256 + threadIdx.x;
  if (i >= NND) return;
  int bi = batch[i];
  int bp = (i > 0) ? batch[i-1] : -1;
  for(int g = bp+1; g <= bi; g++) goff[g] = i;
  if (i == NND-1) for(int g = bi+1; g <= NG; g++) goff[g] = NND;
}

// ---------------- pad + fp32->bf16 for lin1 A (K=143 -> 160) ----------------
__global__ __launch_bounds__(256) void k_padx(const float* __restrict__ x, unsigned short* __restrict__ xp){
  int r = blockIdx.x*4 + (threadIdx.x >> 6);
  int lane = threadIdx.x & 63;
  if (r >= NND) return;
  for(int i = lane; i < FEATP; i += 64)
    xp[(size_t)r*FEATP + i] = (i < FEAT) ? f2b(x[(size_t)r*FEAT + i]) : (unsigned short)0;
}

// ---------------- MFMA GEMM with optional fused row-dot epilogue ----------------
template<int KB, int RT, bool ABF16, bool BIAS, int ACT, bool OBF16, int DOT>
__global__ __launch_bounds__(256) void k_gemm(const void* __restrict__ Ap, int lda,
        const unsigned short* __restrict__ Wf,
        const float* __restrict__ bias, void* __restrict__ Cp, int M,
        const float* __restrict__ v1, const float* __restrict__ v2,
        float* __restrict__ o1, float* __restrict__ o2)
{
  int tid = threadIdx.x, wave = tid >> 6, lane = tid & 63;
  int m = lane & 15, quad = lane >> 4;
  int r0 = blockIdx.x * (16*RT);
  bf8 a[RT][KB];
  #pragma unroll
  for(int rt=0; rt<RT; rt++){
    int row = r0 + rt*16 + m;
    if (ABF16){
      const unsigned short* base = (const unsigned short*)Ap + (size_t)row*lda + quad*8;
      #pragma unroll
      for(int kb=0;kb<KB;kb++) a[rt][kb] = *(const bf8*)(base + kb*32);
    } else {
      const float* base = (const float*)Ap + (size_t)row*lda + quad*8;
      #pragma unroll
      for(int kb=0;kb<KB;kb++) a[rt][kb] = cvt8(base + kb*32);
    }
  }
  float d1[RT][4], d2[RT][4];
  if (DOT >= 1){
    #pragma unroll
    for(int rt=0;rt<RT;rt++)
      #pragma unroll
      for(int i=0;i<4;i++){ d1[rt][i] = 0.f; if (DOT==2) d2[rt][i] = 0.f; }
  }
  #pragma unroll
  for(int ct=0;ct<2;ct++){
    int nt = wave*2 + ct;
    int n = nt*16 + m;
    const bf8* wf = (const bf8*)Wf + (size_t)nt*KB*64;
    bf8 b[KB];
    #pragma unroll
    for(int kb=0;kb<KB;kb++) b[kb] = wf[kb*64 + lane];
    float bv = BIAS ? bias[n] : 0.f;
    float vv1 = (DOT>=1) ? v1[n] : 0.f;
    float vv2 = (DOT==2) ? v2[n] : 0.f;
    #pragma unroll
    for(int rt=0;rt<RT;rt++){
      f4 acc = {0.f,0.f,0.f,0.f};
      #pragma unroll
      for(int kb=0;kb<KB;kb++)
        acc = __builtin_amdgcn_mfma_f32_16x16x32_bf16(a[rt][kb], b[kb], acc, 0, 0, 0);
      #pragma unroll
      for(int i=0;i<4;i++){
        int row = r0 + rt*16 + quad*4 + i;
        float v = acc[i] + bv;
        if (ACT == 1) v = lk(v);
        if (DOT >= 1){ d1[rt][i] += v*vv1; if (DOT==2) d2[rt][i] += v*vv2; }
        if (row < M){
          if (OBF16) ((unsigned short*)Cp)[(size_t)row*H + n] = f2b(v);
          else       ((float*)Cp)[(size_t)row*H + n] = v;
        }
      }
    }
  }
  if (DOT >= 1){
    #pragma unroll
    for(int rt=0;rt<RT;rt++){
      #pragma unroll
      for(int i=0;i<4;i++){
        float dd = d1[rt][i];
        #pragma unroll
        for(int o=1;o<16;o<<=1) dd += __shfl_xor(dd, o);
        int row = r0 + rt*16 + quad*4 + i;
        if (m == 0 && row < M) atomicAdd(&o1[row], dd);
        if (DOT == 2){
          float ee = d2[rt][i];
          #pragma unroll
          for(int o=1;o<16;o<<=1) ee += __shfl_xor(ee, o);
          if (m == 0 && row < M) atomicAdd(&o2[row], ee);
        }
      }
    }
  }
}

// ---------------- dual GEMM for GATEConv: ux = interleave(A@W1^T, A@W2^T) bf16 ----------------
__global__ __launch_bounds__(256) void k_gemm2(const float* __restrict__ A,
        const unsigned short* __restrict__ Wf1, const unsigned short* __restrict__ Wf2,
        unsigned short* __restrict__ ux, int M)
{
  int tid = threadIdx.x, wave = tid >> 6, lane = tid & 63;
  int m = lane & 15, quad = lane >> 4;
  int r0 = blockIdx.x * 64;
  bf8 a[4][4];
  #pragma unroll
  for(int rt=0; rt<4; rt++){
    const float* base = A + (size_t)(r0 + rt*16 + m)*H + quad*8;
    #pragma unroll
    for(int kb=0;kb<4;kb++) a[rt][kb] = cvt8(base + kb*32);
  }
  #pragma unroll
  for(int ws=0; ws<2; ws++){
    const unsigned short* Wf = ws ? Wf2 : Wf1;
    #pragma unroll
    for(int ct=0;ct<2;ct++){
      int nt = wave*2 + ct;
      int n = nt*16 + m;
      const bf8* wf = (const bf8*)Wf + (size_t)nt*256;
      bf8 b[4];
      #pragma unroll
      for(int kb=0;kb<4;kb++) b[kb] = wf[kb*64 + lane];
      int pos = (n>>3)*16 + ws*8 + (n&7);
      #pragma unroll
      for(int rt=0;rt<4;rt++){
        f4 acc = {0.f,0.f,0.f,0.f};
        #pragma unroll
        for(int kb=0;kb<4;kb++)
          acc = __builtin_amdgcn_mfma_f32_16x16x32_bf16(a[rt][kb], b[kb], acc, 0, 0, 0);
        #pragma unroll
        for(int i=0;i<4;i++){
          int row = r0 + rt*16 + quad*4 + i;
          if (row < M) ux[(size_t)row*256 + pos] = f2b(acc[i]);
        }
      }
    }
  }
}

// ---------------- fused MFMA GRU v4 (fragment-ordered weights, 32 rows/block) ----------------
__global__ __launch_bounds__(256) void k_gru(const float* __restrict__ Xin,
      const float* __restrict__ Hid, float* __restrict__ Out,
      const unsigned short* __restrict__ Wif, const unsigned short* __restrict__ Whf,
      const float* __restrict__ bi, const float* __restrict__ bh_)
{
  int tid = threadIdx.x, wave = tid >> 6, lane = tid & 63;
  int m = lane & 15, quad = lane >> 4;
  int r0 = blockIdx.x * 32;
  bf8 ax[2][4], ah[2][4];
  #pragma unroll
  for(int rt=0;rt<2;rt++){
    const float* xb = Xin + (size_t)(r0+rt*16+m)*H + quad*8;
    const float* hb = Hid + (size_t)(r0+rt*16+m)*H + quad*8;
    #pragma unroll
    for(int kb=0;kb<4;kb++){
      ax[rt][kb] = cvt8(xb + kb*32);
      ah[rt][kb] = cvt8(hb + kb*32);
    }
  }
  __syncthreads();   // all A-frag reads of (possibly aliased) Hid done before any store
  f4 rg[2][2], ng[2][2];
  #pragma unroll
  for(int c=0;c<2;c++){
    int nt = wave*2 + c;
    const bf8* wi = (const bf8*)Wif + (size_t)nt*256;
    const bf8* wh = (const bf8*)Whf + (size_t)nt*256;
    int col = nt*16 + m;
    float bb = bi[col] + bh_[col];
    #pragma unroll
    for(int rt=0;rt<2;rt++){
      f4 acc = {0.f,0.f,0.f,0.f};
      #pragma unroll
      for(int kb=0;kb<4;kb++){
        acc = __builtin_amdgcn_mfma_f32_16x16x32_bf16(ax[rt][kb], wi[kb*64+lane], acc,0,0,0);
        acc = __builtin_amdgcn_mfma_f32_16x16x32_bf16(ah[rt][kb], wh[kb*64+lane], acc,0,0,0);
      }
      #pragma unroll
      for(int i=0;i<4;i++) rg[c][rt][i] = sgm(acc[i] + bb);
    }
  }
  #pragma unroll
  for(int c=0;c<2;c++){
    int nt = 16 + wave*2 + c;
    const bf8* wi = (const bf8*)Wif + (size_t)nt*256;
    const bf8* wh = (const bf8*)Whf + (size_t)nt*256;
    int col = (wave*2+c)*16 + m;
    float bin_ = bi[col+256], bhn_ = bh_[col+256];
    #pragma unroll
    for(int rt=0;rt<2;rt++){
      f4 a1 = {0.f,0.f,0.f,0.f}, a2 = {0.f,0.f,0.f,0.f};
      #pragma unroll
      for(int kb=0;kb<4;kb++){
        a1 = __builtin_amdgcn_mfma_f32_16x16x32_bf16(ax[rt][kb], wi[kb*64+lane], a1,0,0,0);
        a2 = __builtin_amdgcn_mfma_f32_16x16x32_bf16(ah[rt][kb], wh[kb*64+lane], a2,0,0,0);
      }
      #pragma unroll
      for(int i=0;i<4;i++)
        ng[c][rt][i] = tanhf(a1[i] + bin_ + rg[c][rt][i]*(a2[i] + bhn_));
    }
  }
  #pragma unroll
  for(int c=0;c<2;c++){
    int nt = 8 + wave*2 + c;
    const bf8* wi = (const bf8*)Wif + (size_t)nt*256;
    const bf8* wh = (const bf8*)Whf + (size_t)nt*256;
    int col = (wave*2+c)*16 + m;
    float bb = bi[col+128] + bh_[col+128];
    #pragma unroll
    for(int rt=0;rt<2;rt++){
      f4 acc = {0.f,0.f,0.f,0.f};
      #pragma unroll
      for(int kb=0;kb<4;kb++){
        acc = __builtin_amdgcn_mfma_f32_16x16x32_bf16(ax[rt][kb], wi[kb*64+lane], acc,0,0,0);
        acc = __builtin_amdgcn_mfma_f32_16x16x32_bf16(ah[rt][kb], wh[kb*64+lane], acc,0,0,0);
      }
      #pragma unroll
      for(int i=0;i<4;i++){
        float zg = sgm(acc[i] + bb);
        int row = r0 + rt*16 + quad*4 + i;
        float hv = Hid[(size_t)row*H + col];
        float o = (1.f - zg)*ng[c][rt][i] + zg*hv;
        Out[(size_t)row*H + col] = fmaxf(o, 0.f);
      }
    }
  }
}

// ---------------- GATEConv: online-softmax aggregation (pre-sorted srcs + eattr) ----------------
__global__ __launch_bounds__(256, 4) void k_gate_agg(
   const float* __restrict__ gcW, const float* __restrict__ attl,
   const float* __restrict__ r, const unsigned short* __restrict__ ux,
   const float* __restrict__ gbias,
   const int* __restrict__ off, const int* __restrict__ srcs, const float* __restrict__ ea_srt,
   float* __restrict__ hout)
{
  int tid = threadIdx.x;
  int wave = tid >> 6, lane = tid & 63;
  int grp = lane >> 4, sub = lane & 15;
  int n = blockIdx.x*4 + wave;
  if (n >= NND) return;
  int c0 = sub*8;
  float W1e[48];        // edge-linear weights for this lane's 8 cols
  #pragma unroll
  for(int c=0;c<8;c++)
    #pragma unroll
    for(int j=0;j<EDIM;j++)
      W1e[c*EDIM+j] = gcW[(size_t)(c0+c)*(H+EDIM) + H + j];
  float attl8[8];
  #pragma unroll
  for(int c=0;c<8;c++) attl8[c] = attl[c0+c];
  int o0 = off[n], deg = off[n+1] - o0;
  float rn = r[n];
  float mx = -3.4e38f, S = 0.f;
  float acc[8] = {0,0,0,0,0,0,0,0};
  for(int base=0; base<deg; base+=64){
    int cnt = min(deg - base, 64);
    int s_l = 0;
    float ea_l[EDIM] = {0,0,0,0,0,0};
    if (lane < cnt){
      int idx = o0 + base + lane;
      s_l = srcs[idx];                       // independent load (no chain)
      const float* ep = ea_srt + (size_t)idx*EDIM;
      #pragma unroll
      for(int j=0;j<EDIM;j++) ea_l[j] = ep[j];   // independent load (no chain)
    }
    #pragma unroll 1
    for(int k=0;k<16;k++){
      int l = grp + k*4;
      if (l >= cnt) break;
      int s = __shfl(s_l, l);
      float ea[EDIM];
      #pragma unroll
      for(int j=0;j<EDIM;j++) ea[j] = __shfl(ea_l[j], l);
      const unsigned short* rowp = ux + (size_t)s*256 + sub*16;
      bf8 uv = *(const bf8*)rowp;
      bf8 xv = *(const bf8*)(rowp + 8);
      float p = 0.f;
      #pragma unroll
      for(int c=0;c<8;c++){
        float ve = 0.f;
        #pragma unroll
        for(int j=0;j<EDIM;j++) ve += ea[j] * W1e[c*EDIM + j];
        float t = lk(b2f((unsigned short)uv[c]) + ve);
        p += t * attl8[c];
      }
      #pragma unroll
      for(int o=1;o<16;o<<=1) p += __shfl_xor(p, o);
      float araw = lk(p + rn);
      float mnew = fmaxf(mx, araw);
      float sc = __expf(mx - mnew);
      float w  = __expf(araw - mnew);
      S = S*sc + w;
      #pragma unroll
      for(int c=0;c<8;c++) acc[c] = acc[c]*sc + w*b2f((unsigned short)xv[c]);
      mx = mnew;
    }
  }
  #pragma unroll
  for(int o=16;o<64;o<<=1){
    float mo = __shfl_xor(mx, o);
    float So = __shfl_xor(S, o);
    float mnew = fmaxf(mx, mo);
    float sa = __expf(mx - mnew), sb = __expf(mo - mnew);
    S = S*sa + So*sb;
    #pragma unroll
    for(int c=0;c<8;c++){
      float ao = __shfl_xor(acc[c], o);
      acc[c] = acc[c]*sa + ao*sb;
    }
    mx = mnew;
  }
  float inv = 1.f/(S + 1e-16f);
  if (grp == 0){
    #pragma unroll
    for(int c=0;c<8;c++)
      hout[(size_t)n*H + c0 + c] = eluf(acc[c]*inv + gbias[c0+c]);
  }
}

// ---------------- atom GATConv: online-softmax aggregation (pre-sorted srcs) ----------------
__global__ __launch_bounds__(256) void k_atom_agg(
    const float* __restrict__ s1, const float* __restrict__ s2,
    const unsigned short* __restrict__ xl, const float* __restrict__ abias,
    const int* __restrict__ off, const int* __restrict__ srcs,
    float* __restrict__ hout)
{
  int tid = threadIdx.x, wave = tid >> 6, lane = tid & 63;
  int grp = lane >> 4, sub = lane & 15;
  int n = blockIdx.x*4 + wave;
  if (n >= NND) return;
  int o0 = off[n], deg = off[n+1] - o0;
  int c0 = sub*8;
  float s2n = s2[n];
  float mx = -3.4e38f, S = 0.f;
  float acc[8] = {0,0,0,0,0,0,0,0};
  for(int base=0; base<deg; base+=64){
    int cnt = min(deg - base, 64);
    int s_l = 0; float ar_l = 0.f;
    if (lane < cnt){ s_l = srcs[o0 + base + lane]; ar_l = lk(s1[s_l] + s2n); }
    #pragma unroll 1
    for(int k=0;k<16;k++){
      int l = grp + k*4;
      if (l >= cnt) break;
      int s = __shfl(s_l, l);
      float araw = __shfl(ar_l, l);
      bf8 xv = *(const bf8*)(xl + (size_t)s*H + c0);
      float mnew = fmaxf(mx, araw);
      float sc = __expf(mx - mnew);
      float w  = __expf(araw - mnew);
      S = S*sc + w;
      #pragma unroll
      for(int c=0;c<8;c++) acc[c] = acc[c]*sc + w*b2f((unsigned short)xv[c]);
      mx = mnew;
    }
  }
  #pragma unroll
  for(int o=16;o<64;o<<=1){
    float mo = __shfl_xor(mx, o);
    float So = __shfl_xor(S, o);
    float mnew = fmaxf(mx, mo);
    float sa = __expf(mx - mnew), sb = __expf(mo - mnew);
    S = S*sa + So*sb;
    #pragma unroll
    for(int c=0;c<8;c++){
      float ao = __shfl_xor(acc[c], o);
      acc[c] = acc[c]*sa + ao*sb;
    }
    mx = mnew;
  }
  float inv = 1.f/(S + 1e-16f);
  if (grp == 0){
    #pragma unroll
    for(int c=0;c<8;c++)
      hout[(size_t)n*H + c0 + c] = eluf(acc[c]*inv + abias[c0+c]);
  }
}

// ---------------- graph readout: out0 = relu(segment_sum(xh)) ----------------
__global__ __launch_bounds__(256) void k_seg0(const float* __restrict__ xh, const int* __restrict__ goff,
                                              float* __restrict__ outg)
{
  int g = blockIdx.x*4 + (threadIdx.x >> 6);
  if (g >= NG) return;
  int lane = threadIdx.x & 63;
  int gs = goff[g], ge = goff[g+1];
  int h0 = lane*2;
  float a0 = 0.f, a1 = 0.f;
  for(int n=gs;n<ge;n++){
    const float* p = xh + (size_t)n*H + h0;
    a0 += p[0]; a1 += p[1];
  }
  outg[(size_t)g*H + h0]   = fmaxf(a0, 0.f);
  outg[(size_t)g*H + h0+1] = fmaxf(a1, 0.f);
}

// ---------------- molecule attention: single-pass online softmax (wave per graph) ----------------
__global__ __launch_bounds__(256) void k_mol_agg(const float* __restrict__ asrc, const float* __restrict__ d,
    const unsigned short* __restrict__ xm, const int* __restrict__ goff,
    const float* __restrict__ mbias, float* __restrict__ hmol)
{
  int tid = threadIdx.x, wave = tid >> 6, lane = tid & 63;
  int grp = lane >> 4, sub = lane & 15;
  int g = blockIdx.x*4 + wave;
  if (g >= NG) return;
  int gs = goff[g], num = goff[g+1] - gs;
  int c0 = sub*8;
  float dg = d[g];
  float mx = -3.4e38f, S = 0.f;
  float acc[8] = {0,0,0,0,0,0,0,0};
  for(int base=0; base<num; base+=64){
    int cnt = min(num - base, 64);
    float ar_l = 0.f;
    if (lane < cnt) ar_l = lk(asrc[gs + base + lane] + dg);
    #pragma unroll 1
    for(int k=0;k<16;k++){
      int l = grp + k*4;
      if (l >= cnt) break;
      float araw = __shfl(ar_l, l);
      int node = gs + base + l;
      bf8 xv = *(const bf8*)(xm + (size_t)node*H + c0);
      float mnew = fmaxf(mx, araw);
      float sc = __expf(mx - mnew);
      float w  = __expf(araw - mnew);
      S = S*sc + w;
      #pragma unroll
      for(int c=0;c<8;c++) acc[c] = acc[c]*sc + w*b2f((unsigned short)xv[c]);
      mx = mnew;
    }
  }
  #pragma unroll
  for(int o=16;o<64;o<<=1){
    float mo = __shfl_xor(mx, o);
    float So = __shfl_xor(S, o);
    float mnew = fmaxf(mx, mo);
    float sa = __expf(mx - mnew), sb = __expf(mo - mnew);
    S = S*sa + So*sb;
    #pragma unroll
    for(int c=0;c<8;c++){
      float ao = __shfl_xor(acc[c], o);
      acc[c] = acc[c]*sa + ao*sb;
    }
    mx = mnew;
  }
  float inv = 1.f/(S + 1e-16f);
  if (grp == 0){
    #pragma unroll
    for(int c=0;c<8;c++)
      hmol[(size_t)g*H + c0 + c] = eluf(acc[c]*inv + mbias[c0+c]);
  }
}

// ---------------- classifier head (wave per graph) -> FP32 output ----------------
__global__ __launch_bounds__(256) void k_cls(const float* __restrict__ emb,
   const float* __restrict__ W1, const float* __restrict__ b1,
   const float* __restrict__ W2, const float* __restrict__ b2,
   float* __restrict__ outp)
{
  __shared__ float W1t[H*64];   // [h][l]
  int tid = threadIdx.x;
  for(int i=tid;i<64*H;i+=256){
    int l = i >> 7, hh = i & 127;
    W1t[hh*64 + l] = W1[i];
  }
  __syncthreads();
  int wave = tid >> 6, lane = tid & 63;
  int g = blockIdx.x*4 + wave;
  if (g >= NG) return;
  const float* er = emb + (size_t)g*H;
  float acc = 0.f;
  for(int hh=0;hh<H;hh++) acc += er[hh] * W1t[hh*64 + lane];
  float hid = fmaxf(acc + b1[lane], 0.f);
  float p = hid * W2[lane];
  p = wsum(p);
  if (lane == 0) outp[g] = p + b2[0];
}

// =====================================================================================
extern "C" void kernel_launch(void* const* d_in, const int* in_sizes, int n_in,
                              void* d_out, int out_size, void* d_ws, size_t ws_size,
                              hipStream_t stream)
{
  const float* x      = (const float*)d_in[0];
  const float* eattr  = (const float*)d_in[1];
  const float* lin1W  = (const float*)d_in[2];
  const float* lin1b  = (const float*)d_in[3];
  const float* gcW    = (const float*)d_in[4];
  const float* gcatl  = (const float*)d_in[5];
  const float* gcatr  = (const float*)d_in[6];
  const float* gcW2   = (const float*)d_in[7];
  const float* gcb    = (const float*)d_in[8];
  const float* g0Wi   = (const float*)d_in[9];
  const float* g0Wh   = (const float*)d_in[10];
  const float* g0bi   = (const float*)d_in[11];
  const float* g0bh   = (const float*)d_in[12];
  const float* aW     = (const float*)d_in[13];
  const float* aas    = (const float*)d_in[14];
  const float* aad    = (const float*)d_in[15];
  const float* ab     = (const float*)d_in[16];
  const float* agWi   = (const float*)d_in[17];
  const float* agWh   = (const float*)d_in[18];
  const float* agbi   = (const float*)d_in[19];
  const float* agbh   = (const float*)d_in[20];
  const float* mW     = (const float*)d_in[21];
  const float* mas    = (const float*)d_in[22];
  const float* mad    = (const float*)d_in[23];
  const float* mb     = (const float*)d_in[24];
  const float* mgWi   = (const float*)d_in[25];
  const float* mgWh   = (const float*)d_in[26];
  const float* mgbi   = (const float*)d_in[27];
  const float* mgbh   = (const float*)d_in[28];
  const float* l2W    = (const float*)d_in[29];
  const float* l2b    = (const float*)d_in[30];
  const float* cW1    = (const float*)d_in[31];
  const float* cb1    = (const float*)d_in[32];
  const float* cW2    = (const float*)d_in[33];
  const float* cb2    = (const float*)d_in[34];
  const int* ei    = (const int*)d_in[35];
  const int* batch = (const int*)d_in[36];
  float* outp = (float*)d_out;

  char* p = (char*)d_ws;
  auto alloc = [&](size_t sz)->void*{ void* q = (void*)p; p += (sz + 511) & ~(size_t)511; return q; };
  float* x0            = (float*)alloc((size_t)NND*H*4);
  unsigned short* ux   = (unsigned short*)alloc((size_t)NND*256*2);  // interleaved u|x2 bf16
  unsigned short* bu   = (unsigned short*)alloc((size_t)NND*H*2);    // bf16 gather target (atom)
  float* xh            = (float*)alloc((size_t)NND*H*4);
  float* bh            = (float*)alloc((size_t)NND*H*4);
  unsigned short* xm   = (unsigned short*)x0;   // alias: x0 dead after first k_gru
  unsigned short* xp   = (unsigned short*)bh;   // alias: bh first written at k_gate_agg (lin1 reads xp before)
  // ---- zeroed block (fused-dot accumulators + CSR degree) ----
  char* z0 = p;
  float* rbuf          = (float*)alloc((size_t)NND*4);
  float* s1a           = (float*)alloc((size_t)NND*4);
  float* s2a           = (float*)alloc((size_t)NND*4);
  float* s1b           = (float*)alloc((size_t)NND*4);
  float* s2b           = (float*)alloc((size_t)NND*4);
  float* asrc          = (float*)alloc((size_t)NND*4);
  float* dg0           = (float*)alloc((size_t)NG*4);
  float* dg1           = (float*)alloc((size_t)NG*4);
  int* deg             = (int*)alloc((size_t)NND*4);
  size_t zbytes = (size_t)(p - z0);
  // ----
  int* off             = (int*)alloc((size_t)(NND+1)*4);
  int* cursor          = (int*)alloc((size_t)NND*4);
  int* srcs            = (int*)alloc((size_t)NED*4);
  float* ea_srt        = (float*)alloc((size_t)NED*EDIM*4);
  int* bsum            = (int*)alloc((size_t)(NBS+1)*4);
  int* goff            = (int*)alloc((size_t)(NG+1)*4);
  float* outg          = (float*)alloc((size_t)NG*H*4);
  float* hmol          = (float*)alloc((size_t)NG*H*4);
  float* om            = (float*)alloc((size_t)NG*H*4);
  float* emb           = (float*)alloc((size_t)NG*H*4);
  // fragment-ordered bf16 weights
  unsigned short* wp     = (unsigned short*)alloc((size_t)8*5*512*2);
  unsigned short* gcWnb  = (unsigned short*)alloc((size_t)H*H*2);
  unsigned short* gcW2b  = (unsigned short*)alloc((size_t)H*H*2);
  unsigned short* g0Wib  = (unsigned short*)alloc((size_t)3*H*H*2);
  unsigned short* g0Whb  = (unsigned short*)alloc((size_t)3*H*H*2);
  unsigned short* aWb    = (unsigned short*)alloc((size_t)2*H*H*2);
  unsigned short* agWib  = (unsigned short*)alloc((size_t)2*3*H*H*2);
  unsigned short* agWhb  = (unsigned short*)alloc((size_t)2*3*H*H*2);
  unsigned short* mWb    = (unsigned short*)alloc((size_t)H*H*2);
  unsigned short* l2Wb   = (unsigned short*)alloc((size_t)H*H*2);
  unsigned short* mgWib  = (unsigned short*)alloc((size_t)3*H*H*2);
  unsigned short* mgWhb  = (unsigned short*)alloc((size_t)3*H*H*2);

  const int HH = H*H, H3H = 3*H*H;
  // single batched fragment-order conversion
  WPack wpk;
  int nd = 0;
  auto addw = [&](const float* s, unsigned short* d, int lds, int srcK, int NT, int KB){
    wpk.d[nd++] = WDesc{s, d, lds, srcK, NT, KB};
  };
  addw(lin1W, wp, FEAT, FEAT, 8, 5);
  addw(gcW, gcWnb, H+EDIM, H, 8, 4);
  addw(gcW2, gcW2b, H, H, 8, 4);
  addw(g0Wi, g0Wib, H, H, 24, 4);
  addw(g0Wh, g0Whb, H, H, 24, 4);
  for(int l=0;l<2;l++){
    addw(aW + (size_t)l*HH, aWb + (size_t)l*HH, H, H, 8, 4);
    addw(agWi + (size_t)l*H3H, agWib + (size_t)l*H3H, H, H, 24, 4);
    addw(agWh + (size_t)l*H3H, agWhb + (size_t)l*H3H, H, H, 24, 4);
  }
  addw(mW, mWb, H, H, 8, 4);
  addw(l2W, l2Wb, H, H, 8, 4);
  addw(mgWi, mgWib, H, H, 24, 4);
  addw(mgWh, mgWhb, H, H, 24, 4);
  wpk.nd = nd;   // 17
  k_wfrag_all<<<nd*WBLK,256,0,stream>>>(wpk);

  // zero accumulators + deg, then CSR build with payload scatter
  hipMemsetAsync(z0, 0, zbytes, stream);
  k_hist<<<1563,256,0,stream>>>(ei, deg);
  k_scan1<<<NBS,256,0,stream>>>(deg, off, bsum);
  k_scan2<<<1,512,0,stream>>>(bsum);
  k_scan3<<<NBS,256,0,stream>>>(off, bsum, cursor);
  k_scatter<<<1563,256,0,stream>>>(ei, eattr, cursor, srcs, ea_srt);
  k_gstart<<<NBS,256,0,stream>>>(batch, goff);

  const int GB = (NND + 63)/64;
  // lin1 + leaky -> x0 fp32, fused dot rbuf = x0 . gcatr
  k_padx<<<25000,256,0,stream>>>(x, xp);
  k_gemm<5,4,true,true,1,false,1><<<GB,256,0,stream>>>(xp, FEATP, wp, lin1b, x0, NND,
                                                       gcatr, nullptr, rbuf, nullptr);
  // GATEConv: dual GEMM -> interleaved ux, then aggregation
  k_gemm2<<<GB,256,0,stream>>>(x0, gcWnb, gcW2b, ux, NND);
  k_gate_agg<<<25000,256,0,stream>>>(gcW, gcatl, rbuf, ux, gcb, off, srcs, ea_srt, bh);
  k_gru<<<NND/32,256,0,stream>>>(bh, x0, xh, g0Wib, g0Whb, g0bi, g0bh);

  // atom GAT layers (fused s1/s2 dots)
  float* s1l[2] = {s1a, s1b};
  float* s2l[2] = {s2a, s2b};
  for(int l=0;l<2;l++){
    k_gemm<4,4,false,false,0,true,2><<<GB,256,0,stream>>>(xh, H, aWb + (size_t)l*HH, nullptr, bu, NND,
                                                          aas + l*H, aad + l*H, s1l[l], s2l[l]);
    k_atom_agg<<<25000,256,0,stream>>>(s1l[l], s2l[l], bu, ab + l*H, off, srcs, bh);
    k_gru<<<NND/32,256,0,stream>>>(bh, xh, xh, agWib + (size_t)l*H3H, agWhb + (size_t)l*H3H,
                                   agbi + l*3*H, agbh + l*3*H);
  }

  // molecule readout (fused asrc dot)
  k_seg0<<<NG/4,256,0,stream>>>(xh, goff, outg);
  k_gemm<4,4,false,false,0,true,1><<<GB,256,0,stream>>>(xh, H, mWb, nullptr, xm, NND,
                                                        mas, nullptr, asrc, nullptr);
  float* dgt[2] = {dg0, dg1};
  for(int t=0;t<2;t++){
    k_gemm<4,4,false,false,0,false,1><<<(NG+63)/64,256,0,stream>>>(outg, H, mWb, nullptr, om, NG,
                                                                   mad, nullptr, dgt[t], nullptr);
    k_mol_agg<<<NG/4,256,0,stream>>>(asrc, dgt[t], xm, goff, mb, hmol);
    k_gru<<<NG/32,256,0,stream>>>(hmol, outg, outg, mgWib, mgWhb, mgbi, mgbh);
  }

  // head
  k_gemm<4,4,false,true,0,false,0><<<(NG+63)/64,256,0,stream>>>(outg, H, l2Wb, l2b, emb, NG,
                                                                nullptr, nullptr, nullptr, nullptr);
  k_cls<<<NG/4,256,0,stream>>>(emb, cW1, cb1, cW2, cb2, outp);
}